// Round 14
// baseline (417.258 us; speedup 1.0000x reference)
//
#include <hip/hip_runtime.h>
#include <hip/hip_bf16.h>

#define NN 50000
#define NE 800000
#define D 64
#define K3 (3 * D)
#define LNEPS 1e-5f
#define STR 68    // f32 LDS row stride (node kernels)
#define SINB 200  // bf16 LDS row stride, edge input tile
#define SHB 72    // bf16 LDS row stride, edge hidden tile
#define MSTR 68   // f32 LDS row stride, msgF reduce tile
#define SEB 68    // f32 LDS row stride (fallback edge kernel)

typedef __attribute__((ext_vector_type(8))) short bf16x8;
typedef __attribute__((ext_vector_type(4))) float f32x4;

// hardware bf16 conversions (RNE)
__device__ __forceinline__ unsigned cvt2(float lo, float hi) {
  __hip_bfloat162 h = __float22bfloat162_rn(make_float2(lo, hi));
  return *(unsigned*)&h;
}
__device__ __forceinline__ unsigned short f2bf(float f) {
  __hip_bfloat16 h = __float2bfloat16(f);
  return *(unsigned short*)&h;
}
__device__ __forceinline__ float bf2f(unsigned short s) {
  return __uint_as_float((unsigned)s << 16);
}

#define FMA4x4(v, w)                                                  \
  a0.x = fmaf(v.x, w.x, a0.x); a0.y = fmaf(v.x, w.y, a0.y);           \
  a0.z = fmaf(v.x, w.z, a0.z); a0.w = fmaf(v.x, w.w, a0.w);           \
  a1.x = fmaf(v.y, w.x, a1.x); a1.y = fmaf(v.y, w.y, a1.y);           \
  a1.z = fmaf(v.y, w.z, a1.z); a1.w = fmaf(v.y, w.w, a1.w);           \
  a2.x = fmaf(v.z, w.x, a2.x); a2.y = fmaf(v.z, w.y, a2.y);           \
  a2.z = fmaf(v.z, w.z, a2.z); a2.w = fmaf(v.z, w.w, a2.w);           \
  a3.x = fmaf(v.w, w.x, a3.x); a3.y = fmaf(v.w, w.y, a3.y);           \
  a3.z = fmaf(v.w, w.z, a3.z); a3.w = fmaf(v.w, w.w, a3.w);

#define FMA2x4(v, w)                                                  \
  a0.x = fmaf(v.x, w.x, a0.x); a0.y = fmaf(v.x, w.y, a0.y);           \
  a0.z = fmaf(v.x, w.z, a0.z); a0.w = fmaf(v.x, w.w, a0.w);           \
  a1.x = fmaf(v.y, w.x, a1.x); a1.y = fmaf(v.y, w.y, a1.y);           \
  a1.z = fmaf(v.y, w.z, a1.z); a1.w = fmaf(v.y, w.w, a1.w);

#define HSTORE_RELU(buf)                                              \
  buf[(j0+0)*STR + t0+0] = fmaxf(a0.x, 0.f);                          \
  buf[(j0+1)*STR + t0+0] = fmaxf(a0.y, 0.f);                          \
  buf[(j0+2)*STR + t0+0] = fmaxf(a0.z, 0.f);                          \
  buf[(j0+3)*STR + t0+0] = fmaxf(a0.w, 0.f);                          \
  buf[(j0+0)*STR + t0+1] = fmaxf(a1.x, 0.f);                          \
  buf[(j0+1)*STR + t0+1] = fmaxf(a1.y, 0.f);                          \
  buf[(j0+2)*STR + t0+1] = fmaxf(a1.z, 0.f);                          \
  buf[(j0+3)*STR + t0+1] = fmaxf(a1.w, 0.f);                          \
  buf[(j0+0)*STR + t0+2] = fmaxf(a2.x, 0.f);                          \
  buf[(j0+1)*STR + t0+2] = fmaxf(a2.y, 0.f);                          \
  buf[(j0+2)*STR + t0+2] = fmaxf(a2.z, 0.f);                          \
  buf[(j0+3)*STR + t0+2] = fmaxf(a2.w, 0.f);                          \
  buf[(j0+0)*STR + t0+3] = fmaxf(a3.x, 0.f);                          \
  buf[(j0+1)*STR + t0+3] = fmaxf(a3.y, 0.f);                          \
  buf[(j0+2)*STR + t0+3] = fmaxf(a3.z, 0.f);                          \
  buf[(j0+3)*STR + t0+3] = fmaxf(a3.w, 0.f);

// ---------------- zero kernels ----------------
__global__ __launch_bounds__(256) void zero_int_kernel(int* __restrict__ p, int n) {
  int i = blockIdx.x * 256 + threadIdx.x;
  if (i < n) p[i] = 0;
}
__global__ __launch_bounds__(256) void zero_f4_kernel(float4* __restrict__ p, int n) {
  int i = blockIdx.x * 256 + threadIdx.x;
  if (i < n) p[i] = make_float4(0.f, 0.f, 0.f, 0.f);
}

// ---------------- CSR build ----------------
__global__ __launch_bounds__(256) void count_kernel(
    const int* __restrict__ dst, int* __restrict__ deg) {
  int e = blockIdx.x * 256 + threadIdx.x;
  if (e < NE) atomicAdd(&deg[dst[e]], 1);
}

__global__ __launch_bounds__(1024) void scan_reduce_kernel(
    const int* __restrict__ deg, int* __restrict__ bsum) {
  __shared__ int sS[16];
  int i = blockIdx.x * 1024 + threadIdx.x;
  int v = (i < NN) ? deg[i] : 0;
#pragma unroll
  for (int o = 32; o > 0; o >>= 1) v += __shfl_down(v, o, 64);
  if ((threadIdx.x & 63) == 0) sS[threadIdx.x >> 6] = v;
  __syncthreads();
  if (threadIdx.x == 0) {
    int s = 0;
#pragma unroll
    for (int k = 0; k < 16; ++k) s += sS[k];
    bsum[blockIdx.x] = s;
  }
}

__global__ __launch_bounds__(1024) void scan_final_kernel(
    const int* __restrict__ deg, const int* __restrict__ bsum,
    int* __restrict__ off, int* __restrict__ cur) {
  __shared__ int sD[1024];
  __shared__ int sOfs;
  const int t = threadIdx.x;
  const int b = blockIdx.x;
  int i = b * 1024 + t;
  int v = (i < NN) ? deg[i] : 0;
  sD[t] = v;
  if (t == 0) {
    int o = 0;
    for (int k = 0; k < b; ++k) o += bsum[k];
    sOfs = o;
  }
  __syncthreads();
  for (int st = 1; st < 1024; st <<= 1) {
    int add = (t >= st) ? sD[t - st] : 0;
    __syncthreads();
    sD[t] += add;
    __syncthreads();
  }
  if (i < NN) {
    int excl = sOfs + sD[t] - v;
    off[i] = excl;
    cur[i] = excl;
    if (i == NN - 1) off[NN] = NE;
  }
}

// epair[p] = {eid, src[eid]}, dcsr[p] = dst[eid], pos[eid] = p
__global__ __launch_bounds__(256) void fill_kernel(
    const int* __restrict__ src, const int* __restrict__ dst,
    int* __restrict__ cur, int2* __restrict__ epair,
    int* __restrict__ dcsr, int* __restrict__ pos) {
  int e = blockIdx.x * 256 + threadIdx.x;
  if (e < NE) {
    int d = dst[e];
    int p = atomicAdd(&cur[d], 1);
    epair[p] = make_int2(e, src[e]);
    dcsr[p] = d;
    pos[e] = p;
  }
}

// ---------------- permute e0 into CSR order (bf16) + layer-0 message ----------------
// streaming read of e; x0[src] random read (L2/L3-hot, 12.8 MB footprint);
// scattered 32B-granule writes to ecsr and msg0 (fire-and-forget).
__global__ __launch_bounds__(256) void permute_e_kernel(
    const float* __restrict__ e, const float* __restrict__ x,
    const int* __restrict__ src, const int* __restrict__ pos,
    unsigned short* __restrict__ ecsr, unsigned short* __restrict__ msg0) {
  int tid = blockIdx.x * 256 + threadIdx.x;  // NE*4 threads
  int eid = tid >> 2, q = tid & 3;
  if (eid >= NE) return;
  int p = pos[eid];
  int s = src[eid];
  const float4* ep = (const float4*)(e + (size_t)eid * D + q * 16);
  const float4* xp = (const float4*)(x + (size_t)s * D + q * 16);
  float4 v0 = ep[0], v1 = ep[1], v2 = ep[2], v3 = ep[3];
  float4 y0 = xp[0], y1 = xp[1], y2 = xp[2], y3 = xp[3];
  uint4 u0, u1;
  u0.x = cvt2(v0.x, v0.y); u0.y = cvt2(v0.z, v0.w);
  u0.z = cvt2(v1.x, v1.y); u0.w = cvt2(v1.z, v1.w);
  u1.x = cvt2(v2.x, v2.y); u1.y = cvt2(v2.z, v2.w);
  u1.z = cvt2(v3.x, v3.y); u1.w = cvt2(v3.z, v3.w);
  uint4* ed = (uint4*)(ecsr + (size_t)p * D + q * 16);
  ed[0] = u0;
  ed[1] = u1;
  // msg0 = relu(x0[src] + e)
  uint4 m0, m1;
  m0.x = cvt2(fmaxf(y0.x + v0.x, 0.f), fmaxf(y0.y + v0.y, 0.f));
  m0.y = cvt2(fmaxf(y0.z + v0.z, 0.f), fmaxf(y0.w + v0.w, 0.f));
  m0.z = cvt2(fmaxf(y1.x + v1.x, 0.f), fmaxf(y1.y + v1.y, 0.f));
  m0.w = cvt2(fmaxf(y1.z + v1.z, 0.f), fmaxf(y1.w + v1.w, 0.f));
  m1.x = cvt2(fmaxf(y2.x + v2.x, 0.f), fmaxf(y2.y + v2.y, 0.f));
  m1.y = cvt2(fmaxf(y2.z + v2.z, 0.f), fmaxf(y2.w + v2.w, 0.f));
  m1.z = cvt2(fmaxf(y3.x + v3.x, 0.f), fmaxf(y3.y + v3.y, 0.f));
  m1.w = cvt2(fmaxf(y3.z + v3.z, 0.f), fmaxf(y3.w + v3.w, 0.f));
  uint4* md = (uint4*)(msg0 + (size_t)p * D + q * 16);
  md[0] = m0;
  md[1] = m1;
}

// ---------------- pack edge-MLP weights ----------------
__global__ __launch_bounds__(256) void pack_weights_kernel(
    const float* __restrict__ w1, const float* __restrict__ w2,
    unsigned short* __restrict__ wB1, unsigned short* __restrict__ wB2) {
  int tid = blockIdx.x * 256 + threadIdx.x;
  const float* wsrc;
  unsigned short* wdst;
  int kb, j, slot;
  if (tid < 1536) {
    int nt = tid / 384, kk = (tid / 64) % 6, l = tid & 63;
    kb = kk * 32 + (l >> 4) * 8;
    j = nt * 16 + (l & 15);
    wsrc = w1; wdst = wB1; slot = tid;
  } else {
    int t = tid - 1536;
    int nt = t / 128, kk = (t / 64) & 1, l = t & 63;
    kb = kk * 32 + (l >> 4) * 8;
    j = nt * 16 + (l & 15);
    wsrc = w2; wdst = wB2; slot = t;
  }
  unsigned short b[8];
#pragma unroll
  for (int i = 0; i < 8; ++i) b[i] = f2bf(wsrc[(kb + i) * D + j]);
  uint4 v;
  v.x = (unsigned)b[0] | ((unsigned)b[1] << 16);
  v.y = (unsigned)b[2] | ((unsigned)b[3] << 16);
  v.z = (unsigned)b[4] | ((unsigned)b[5] << 16);
  v.w = (unsigned)b[6] | ((unsigned)b[7] << 16);
  *(uint4*)(wdst + (size_t)slot * 8) = v;
}

// ---------------- 512-thread MLP tail ----------------
__device__ __forceinline__ void mlp_tail512(
    float* sIN, float* sH, float* sPS, float* sPQ, float* sMu, float* sRs,
    const float* __restrict__ w1, const float* __restrict__ b1,
    const float* __restrict__ w2, const float* __restrict__ b2,
    const float* __restrict__ g, const float* __restrict__ bln,
    float* __restrict__ xo, unsigned short* __restrict__ xob,
    const float* __restrict__ hw, const float* __restrict__ hb,
    float* __restrict__ outh,
    int n0, int tid) {
  __syncthreads();
  const int tj = tid & 15, tt = tid >> 4;   // 16 x 32
  const int j0 = tj * 4, t0 = tt * 2;
  float4 a0, a1;

  {
    float4 bv = *(const float4*)(b1 + j0);
    a0 = a1 = bv;
    for (int k = 0; k < D; ++k) {
      float4 w = *(const float4*)(w1 + k * D + j0);
      float2 v = *(const float2*)&sIN[k * STR + t0];
      FMA2x4(v, w)
    }
  }
  sH[(j0 + 0) * STR + t0 + 0] = fmaxf(a0.x, 0.f);
  sH[(j0 + 1) * STR + t0 + 0] = fmaxf(a0.y, 0.f);
  sH[(j0 + 2) * STR + t0 + 0] = fmaxf(a0.z, 0.f);
  sH[(j0 + 3) * STR + t0 + 0] = fmaxf(a0.w, 0.f);
  sH[(j0 + 0) * STR + t0 + 1] = fmaxf(a1.x, 0.f);
  sH[(j0 + 1) * STR + t0 + 1] = fmaxf(a1.y, 0.f);
  sH[(j0 + 2) * STR + t0 + 1] = fmaxf(a1.z, 0.f);
  sH[(j0 + 3) * STR + t0 + 1] = fmaxf(a1.w, 0.f);
  __syncthreads();

  {
    float4 bv = *(const float4*)(b2 + j0);
    a0 = a1 = bv;
    for (int k = 0; k < D; ++k) {
      float4 w = *(const float4*)(w2 + k * D + j0);
      float2 v = *(const float2*)&sH[k * STR + t0];
      FMA2x4(v, w)
    }
  }
  __syncthreads();
  *(float4*)&sH[(t0 + 0) * STR + j0] = a0;
  *(float4*)&sH[(t0 + 1) * STR + j0] = a1;
  __syncthreads();

  {
    const int t = tid & 63, p = tid >> 6;
    const float* r = &sH[t * STR + p * 8];
    float s = 0.f, q = 0.f;
#pragma unroll
    for (int i = 0; i < 8; ++i) { float v = r[i]; s += v; q = fmaf(v, v, q); }
    sPS[p * 64 + t] = s;
    sPQ[p * 64 + t] = q;
  }
  __syncthreads();
  if (tid < 64) {
    float s = 0.f, q = 0.f;
#pragma unroll
    for (int p = 0; p < 8; ++p) { s += sPS[p * 64 + tid]; q += sPQ[p * 64 + tid]; }
    float mu = s * (1.f / 64.f);
    float var = q * (1.f / 64.f) - mu * mu;
    sMu[tid] = mu;
    sRs[tid] = rsqrtf(var + LNEPS);
  }
  __syncthreads();

  {
    const int t = tid >> 3, c = (tid & 7) * 8;
    int node = n0 + t;
    if (node < NN) {
      float mu = sMu[t], rs = sRs[t];
      float4 v0 = *(const float4*)&sH[t * STR + c + 0];
      float4 v1 = *(const float4*)&sH[t * STR + c + 4];
      float4 g0v = *(const float4*)(g + c + 0);
      float4 g1v = *(const float4*)(g + c + 4);
      float4 b0v = *(const float4*)(bln + c + 0);
      float4 b1v = *(const float4*)(bln + c + 4);
      float4 r0, r1;
      r0.x = fmaxf(fmaf((v0.x - mu) * rs, g0v.x, b0v.x), 0.f);
      r0.y = fmaxf(fmaf((v0.y - mu) * rs, g0v.y, b0v.y), 0.f);
      r0.z = fmaxf(fmaf((v0.z - mu) * rs, g0v.z, b0v.z), 0.f);
      r0.w = fmaxf(fmaf((v0.w - mu) * rs, g0v.w, b0v.w), 0.f);
      r1.x = fmaxf(fmaf((v1.x - mu) * rs, g1v.x, b1v.x), 0.f);
      r1.y = fmaxf(fmaf((v1.y - mu) * rs, g1v.y, b1v.y), 0.f);
      r1.z = fmaxf(fmaf((v1.z - mu) * rs, g1v.z, b1v.z), 0.f);
      r1.w = fmaxf(fmaf((v1.w - mu) * rs, g1v.w, b1v.w), 0.f);
      if (outh) {
        float h0, h1;
        h0 = r0.x * hw[(c + 0) * 2 + 0] + r0.y * hw[(c + 1) * 2 + 0] +
             r0.z * hw[(c + 2) * 2 + 0] + r0.w * hw[(c + 3) * 2 + 0] +
             r1.x * hw[(c + 4) * 2 + 0] + r1.y * hw[(c + 5) * 2 + 0] +
             r1.z * hw[(c + 6) * 2 + 0] + r1.w * hw[(c + 7) * 2 + 0];
        h1 = r0.x * hw[(c + 0) * 2 + 1] + r0.y * hw[(c + 1) * 2 + 1] +
             r0.z * hw[(c + 2) * 2 + 1] + r0.w * hw[(c + 3) * 2 + 1] +
             r1.x * hw[(c + 4) * 2 + 1] + r1.y * hw[(c + 5) * 2 + 1] +
             r1.z * hw[(c + 6) * 2 + 1] + r1.w * hw[(c + 7) * 2 + 1];
#pragma unroll
        for (int o = 1; o < 8; o <<= 1) {
          h0 += __shfl_xor(h0, o, 64);
          h1 += __shfl_xor(h1, o, 64);
        }
        if ((tid & 7) == 0) {
          outh[node * 2 + 0] = h0 + hb[0];
          outh[node * 2 + 1] = h1 + hb[1];
        }
      } else {
        if (xo) {
          float* o = xo + (size_t)node * D + c;
          ((float4*)o)[0] = r0;
          ((float4*)o)[1] = r1;
        }
        if (xob) {
          uint4 u;
          u.x = cvt2(r0.x, r0.y); u.y = cvt2(r0.z, r0.w);
          u.z = cvt2(r1.x, r1.y); u.w = cvt2(r1.z, r1.w);
          *(uint4*)(xob + (size_t)node * D + c) = u;
        }
      }
    }
  }
}

// ---------------- layer-0: streaming msg0 segment-sum + node MLP -> x1b ----------------
__global__ __launch_bounds__(512) void node_mlp_g0_kernel(
    const float* __restrict__ x, const unsigned short* __restrict__ msg0,
    const int* __restrict__ off,
    const float* __restrict__ w1, const float* __restrict__ b1,
    const float* __restrict__ w2, const float* __restrict__ b2,
    const float* __restrict__ g, const float* __restrict__ bln,
    unsigned short* __restrict__ xob) {
  __shared__ float sIN[D * STR];
  __shared__ float sH[D * STR];
  __shared__ float sPS[512], sPQ[512], sMu[64], sRs[64];
  const int tid = threadIdx.x;
  const int n0 = blockIdx.x * 64;
  const int wv = tid >> 6, lane = tid & 63;
  for (int q = 0; q < 8; ++q) {
    int t = wv * 8 + q;
    int node = n0 + t;
    float acc = 0.f;
    if (node < NN) {
      acc = x[(size_t)node * D + lane];  // self term
      int beg = off[node], end = off[node + 1];
      const unsigned short* mr = msg0 + (size_t)beg * D + lane;
      int cnt = end - beg, i = 0;
      for (; i + 3 < cnt; i += 4) {
        float m0 = bf2f(mr[(size_t)(i + 0) * D]);
        float m1 = bf2f(mr[(size_t)(i + 1) * D]);
        float m2 = bf2f(mr[(size_t)(i + 2) * D]);
        float m3 = bf2f(mr[(size_t)(i + 3) * D]);
        acc += (m0 + m1) + (m2 + m3);
      }
      for (; i < cnt; ++i) acc += bf2f(mr[(size_t)i * D]);
    }
    sIN[lane * STR + t] = acc;
  }
  mlp_tail512(sIN, sH, sPS, sPQ, sMu, sRs, w1, b1, w2, b2, g, bln,
              nullptr, xob, nullptr, nullptr, nullptr, n0, tid);
}

// ---------------- layer-1: plain node MLP (x1b + agg) + fused head ----------------
__global__ __launch_bounds__(512) void node_mlp1_kernel(
    const unsigned short* __restrict__ xb, const float* __restrict__ agg,
    const float* __restrict__ w1, const float* __restrict__ b1,
    const float* __restrict__ w2, const float* __restrict__ b2,
    const float* __restrict__ g, const float* __restrict__ bln,
    const float* __restrict__ hw, const float* __restrict__ hb,
    float* __restrict__ outh) {
  __shared__ float sIN[D * STR];
  __shared__ float sH[D * STR];
  __shared__ float sPS[512], sPQ[512], sMu[64], sRs[64];
  const int tid = threadIdx.x;
  const int n0 = blockIdx.x * 64;
  {
    const int t = tid & 63, p = tid >> 6;  // 8 feats each
    int node = n0 + t;
    int cn = node < NN ? node : 0;
    const unsigned short* xr = xb + (size_t)cn * D + p * 8;
    const float* ar = agg + (size_t)cn * D + p * 8;
    uint4 xv = *(const uint4*)xr;
    float4 a0v = ((const float4*)ar)[0];
    float4 a1v = ((const float4*)ar)[1];
    int k = p * 8;
    sIN[(k + 0) * STR + t] = bf2f((unsigned short)(xv.x & 0xFFFF)) + a0v.x;
    sIN[(k + 1) * STR + t] = bf2f((unsigned short)(xv.x >> 16)) + a0v.y;
    sIN[(k + 2) * STR + t] = bf2f((unsigned short)(xv.y & 0xFFFF)) + a0v.z;
    sIN[(k + 3) * STR + t] = bf2f((unsigned short)(xv.y >> 16)) + a0v.w;
    sIN[(k + 4) * STR + t] = bf2f((unsigned short)(xv.z & 0xFFFF)) + a1v.x;
    sIN[(k + 5) * STR + t] = bf2f((unsigned short)(xv.z >> 16)) + a1v.y;
    sIN[(k + 6) * STR + t] = bf2f((unsigned short)(xv.w & 0xFFFF)) + a1v.z;
    sIN[(k + 7) * STR + t] = bf2f((unsigned short)(xv.w >> 16)) + a1v.w;
  }
  mlp_tail512(sIN, sH, sPS, sPQ, sMu, sRs, w1, b1, w2, b2, g, bln,
              nullptr, nullptr, hw, hb, outh, n0, tid);
}

// ---------------- MFMA edge MLP + parallel in-LDS segment reduce -> agg atomics ----------------
__global__ __launch_bounds__(256) void edge_mfma_seg_kernel(
    const unsigned short* __restrict__ x1b, const unsigned short* __restrict__ ecsr,
    const int2* __restrict__ epair, const int* __restrict__ dcsr,
    const unsigned short* __restrict__ wB1, const float* __restrict__ b1,
    const unsigned short* __restrict__ wB2, const float* __restrict__ b2,
    float* __restrict__ agg) {
  __shared__ unsigned short sIN[64 * SINB];  // reused as f32 msgF[64][MSTR]
  __shared__ unsigned short sH[64 * SHB];
  __shared__ int sDst[64];

  const int tid = threadIdx.x;
  const int e0 = blockIdx.x * 64;  // CSR slot base
  const int lane = tid & 63;
  const int mt = tid >> 6;
  const int hl = lane >> 4;
  const int ll = lane & 15;

  {
    const int t = tid & 63, p = tid >> 6;
    int slot = e0 + t;
    int sN = epair[slot].y;
    int dN = dcsr[slot];
    if (p == 0) sDst[t] = dN;
    const uint4* xs = (const uint4*)(x1b + (size_t)sN * D + p * 16);
    const uint4* xd = (const uint4*)(x1b + (size_t)dN * D + p * 16);
    const uint4* ec = (const uint4*)(ecsr + (size_t)slot * D + p * 16);
    uint4* r0 = (uint4*)(sIN + t * SINB + p * 16);
    uint4* r1 = (uint4*)(sIN + t * SINB + 64 + p * 16);
    uint4* r2 = (uint4*)(sIN + t * SINB + 128 + p * 16);
    uint4 a0v = xs[0], a1v = xs[1];
    uint4 b0v = xd[0], b1v = xd[1];
    uint4 c0v = ec[0], c1v = ec[1];
    r0[0] = a0v; r0[1] = a1v;
    r1[0] = b0v; r1[1] = b1v;
    r2[0] = c0v; r2[1] = c1v;
  }
  __syncthreads();

  f32x4 acc[4];
#pragma unroll
  for (int nt = 0; nt < 4; ++nt) {
    float b = b1[nt * 16 + ll];
    acc[nt].x = b; acc[nt].y = b; acc[nt].z = b; acc[nt].w = b;
  }
  {
    const unsigned short* aBase = sIN + (mt * 16 + ll) * SINB + hl * 8;
#pragma unroll
    for (int kk = 0; kk < 6; ++kk) {
      bf16x8 af = *(const bf16x8*)(aBase + kk * 32);
#pragma unroll
      for (int nt = 0; nt < 4; ++nt) {
        bf16x8 bf = *(const bf16x8*)(wB1 + ((size_t)(nt * 6 + kk) * 64 + lane) * 8);
        acc[nt] = __builtin_amdgcn_mfma_f32_16x16x32_bf16(af, bf, acc[nt], 0, 0, 0);
      }
    }
  }
#pragma unroll
  for (int nt = 0; nt < 4; ++nt)
#pragma unroll
    for (int r = 0; r < 4; ++r)
      sH[(mt * 16 + hl * 4 + r) * SHB + nt * 16 + ll] = f2bf(fmaxf(acc[nt][r], 0.f));
  __syncthreads();

  f32x4 acc2[4];
#pragma unroll
  for (int nt = 0; nt < 4; ++nt) {
    float b = b2[nt * 16 + ll];
    acc2[nt].x = b; acc2[nt].y = b; acc2[nt].z = b; acc2[nt].w = b;
  }
  {
    const unsigned short* hBase = sH + (mt * 16 + ll) * SHB + hl * 8;
#pragma unroll
    for (int kk = 0; kk < 2; ++kk) {
      bf16x8 af = *(const bf16x8*)(hBase + kk * 32);
#pragma unroll
      for (int nt = 0; nt < 4; ++nt) {
        bf16x8 bf = *(const bf16x8*)(wB2 + ((size_t)(nt * 2 + kk) * 64 + lane) * 8);
        acc2[nt] = __builtin_amdgcn_mfma_f32_16x16x32_bf16(af, bf, acc2[nt], 0, 0, 0);
      }
    }
  }

  float m0x, m0y, m0z, m0w, m1x, m1y, m1z, m1w;
  float m2x, m2y, m2z, m2w, m3x, m3y, m3z, m3w;
  {
    const unsigned short* x0r = sIN + (mt * 16 + hl * 4 + 0) * SINB;
    const unsigned short* x1r = sIN + (mt * 16 + hl * 4 + 1) * SINB;
    const unsigned short* x2r = sIN + (mt * 16 + hl * 4 + 2) * SINB;
    const unsigned short* x3r = sIN + (mt * 16 + hl * 4 + 3) * SINB;
#define MSG(xr, nt, r) fmaxf(bf2f(xr[nt * 16 + ll]) + fmaf(0.5f, acc2[nt][r], bf2f(xr[128 + nt * 16 + ll])), 0.f)
    m0x = MSG(x0r, 0, 0); m0y = MSG(x0r, 1, 0); m0z = MSG(x0r, 2, 0); m0w = MSG(x0r, 3, 0);
    m1x = MSG(x1r, 0, 1); m1y = MSG(x1r, 1, 1); m1z = MSG(x1r, 2, 1); m1w = MSG(x1r, 3, 1);
    m2x = MSG(x2r, 0, 2); m2y = MSG(x2r, 1, 2); m2z = MSG(x2r, 2, 2); m2w = MSG(x2r, 3, 2);
    m3x = MSG(x3r, 0, 3); m3y = MSG(x3r, 1, 3); m3z = MSG(x3r, 2, 3); m3w = MSG(x3r, 3, 3);
#undef MSG
  }
  __syncthreads();

  float* msgF = (float*)sIN;  // [64][MSTR]
  {
    int tb = mt * 16 + hl * 4;
    msgF[(tb + 0) * MSTR + 0 * 16 + ll] = m0x;
    msgF[(tb + 0) * MSTR + 1 * 16 + ll] = m0y;
    msgF[(tb + 0) * MSTR + 2 * 16 + ll] = m0z;
    msgF[(tb + 0) * MSTR + 3 * 16 + ll] = m0w;
    msgF[(tb + 1) * MSTR + 0 * 16 + ll] = m1x;
    msgF[(tb + 1) * MSTR + 1 * 16 + ll] = m1y;
    msgF[(tb + 1) * MSTR + 2 * 16 + ll] = m1z;
    msgF[(tb + 1) * MSTR + 3 * 16 + ll] = m1w;
    msgF[(tb + 2) * MSTR + 0 * 16 + ll] = m2x;
    msgF[(tb + 2) * MSTR + 1 * 16 + ll] = m2y;
    msgF[(tb + 2) * MSTR + 2 * 16 + ll] = m2z;
    msgF[(tb + 2) * MSTR + 3 * 16 + ll] = m2w;
    msgF[(tb + 3) * MSTR + 0 * 16 + ll] = m3x;
    msgF[(tb + 3) * MSTR + 1 * 16 + ll] = m3y;
    msgF[(tb + 3) * MSTR + 2 * 16 + ll] = m3z;
    msgF[(tb + 3) * MSTR + 3 * 16 + ll] = m3w;
  }
  __syncthreads();

  {
    const int p = tid >> 6, j = tid & 63;
    const int rbeg = p * 16, rend = rbeg + 16;
    int cur = sDst[rbeg];
    float sum = msgF[rbeg * MSTR + j];
    for (int t = rbeg + 1; t < rend; ++t) {
      int d = sDst[t];
      float v = msgF[t * MSTR + j];
      if (d != cur) {
        atomicAdd(&agg[(size_t)cur * D + j], sum);
        cur = d;
        sum = v;
      } else {
        sum += v;
      }
    }
    atomicAdd(&agg[(size_t)cur * D + j], sum);
  }
}

// ---------------- legacy kernels (fallback tier) ----------------
__global__ __launch_bounds__(256) void scatter_kernel(
    const float* __restrict__ x, const float* __restrict__ e,
    const int* __restrict__ src, const int* __restrict__ dst,
    float* __restrict__ agg) {
  int tid = blockIdx.x * blockDim.x + threadIdx.x;
  if (tid >= NE * 16) return;
  int eid = tid >> 4, q = tid & 15;
  int s = src[eid], d = dst[eid];
  float4 xv = ((const float4*)(x + (size_t)s * D))[q];
  float4 ev = ((const float4*)(e + (size_t)eid * D))[q];
  float* a = agg + (size_t)d * D + q * 4;
  atomicAdd(a + 0, fmaxf(xv.x + ev.x, 0.f));
  atomicAdd(a + 1, fmaxf(xv.y + ev.y, 0.f));
  atomicAdd(a + 2, fmaxf(xv.z + ev.z, 0.f));
  atomicAdd(a + 3, fmaxf(xv.w + ev.w, 0.f));
}

__device__ __forceinline__ void mlp_tail256(
    float* sIN, float* sH, float* sPS, float* sPQ, float* sMu, float* sRs,
    const float* __restrict__ w1, const float* __restrict__ b1,
    const float* __restrict__ w2, const float* __restrict__ b2,
    const float* __restrict__ g, const float* __restrict__ bln,
    float* __restrict__ xo, int n0, int tid) {
  __syncthreads();
  const int tj = tid & 15, tt = tid >> 4;
  const int j0 = tj * 4, t0 = tt * 4;
  float4 a0, a1, a2, a3;
  {
    float4 bv = *(const float4*)(b1 + j0);
    a0 = a1 = a2 = a3 = bv;
    for (int k = 0; k < D; ++k) {
      float4 w = *(const float4*)(w1 + k * D + j0);
      float4 v = *(const float4*)&sIN[k * STR + t0];
      FMA4x4(v, w)
    }
  }
  HSTORE_RELU(sH)
  __syncthreads();
  {
    float4 bv = *(const float4*)(b2 + j0);
    a0 = a1 = a2 = a3 = bv;
    for (int k = 0; k < D; ++k) {
      float4 w = *(const float4*)(w2 + k * D + j0);
      float4 v = *(const float4*)&sH[k * STR + t0];
      FMA4x4(v, w)
    }
  }
  __syncthreads();
  *(float4*)&sH[(t0 + 0) * STR + j0] = a0;
  *(float4*)&sH[(t0 + 1) * STR + j0] = a1;
  *(float4*)&sH[(t0 + 2) * STR + j0] = a2;
  *(float4*)&sH[(t0 + 3) * STR + j0] = a3;
  __syncthreads();
  {
    const int t = tid & 63, p = tid >> 6;
    const float* r = &sH[t * STR + p * 16];
    float s = 0.f, q = 0.f;
#pragma unroll
    for (int i = 0; i < 16; ++i) { float v = r[i]; s += v; q = fmaf(v, v, q); }
    sPS[p * 64 + t] = s;
    sPQ[p * 64 + t] = q;
  }
  __syncthreads();
  if (tid < 64) {
    float s = sPS[tid] + sPS[64 + tid] + sPS[128 + tid] + sPS[192 + tid];
    float q = sPQ[tid] + sPQ[64 + tid] + sPQ[128 + tid] + sPQ[192 + tid];
    float mu = s * (1.f / 64.f);
    float var = q * (1.f / 64.f) - mu * mu;
    sMu[tid] = mu;
    sRs[tid] = rsqrtf(var + LNEPS);
  }
  __syncthreads();
  {
    const int t = tid >> 2, c = (tid & 3) * 16;
    int node = n0 + t;
    if (node < NN) {
      float mu = sMu[t], rs = sRs[t];
      float* o = xo + (size_t)node * D + c;
#pragma unroll
      for (int i = 0; i < 4; ++i) {
        float4 v = *(const float4*)&sH[t * STR + c + i * 4];
        float4 gv = *(const float4*)(g + c + i * 4);
        float4 bv = *(const float4*)(bln + c + i * 4);
        float4 r;
        r.x = fmaxf(fmaf((v.x - mu) * rs, gv.x, bv.x), 0.f);
        r.y = fmaxf(fmaf((v.y - mu) * rs, gv.y, bv.y), 0.f);
        r.z = fmaxf(fmaf((v.z - mu) * rs, gv.z, bv.z), 0.f);
        r.w = fmaxf(fmaf((v.w - mu) * rs, gv.w, bv.w), 0.f);
        ((float4*)o)[i] = r;
      }
    }
  }
}

__global__ __launch_bounds__(256) void node_mlp_kernel(
    const float* __restrict__ x, const float* __restrict__ agg,
    const float* __restrict__ w1, const float* __restrict__ b1,
    const float* __restrict__ w2, const float* __restrict__ b2,
    const float* __restrict__ g, const float* __restrict__ bln,
    float* __restrict__ xo) {
  __shared__ float sIN[D * STR];
  __shared__ float sH[D * STR];
  __shared__ float sPS[256], sPQ[256], sMu[64], sRs[64];
  const int tid = threadIdx.x;
  const int n0 = blockIdx.x * 64;
  {
    const int t = tid & 63, p = tid >> 6;
    int node = n0 + t;
    int cn = node < NN ? node : 0;
    const float* xr = x + (size_t)cn * D + p * 16;
    const float* ar = agg + (size_t)cn * D + p * 16;
#pragma unroll
    for (int i = 0; i < 4; ++i) {
      float4 xv = ((const float4*)xr)[i];
      float4 av = ((const float4*)ar)[i];
      int k = p * 16 + i * 4;
      sIN[(k + 0) * STR + t] = xv.x + av.x;
      sIN[(k + 1) * STR + t] = xv.y + av.y;
      sIN[(k + 2) * STR + t] = xv.z + av.z;
      sIN[(k + 3) * STR + t] = xv.w + av.w;
    }
  }
  mlp_tail256(sIN, sH, sPS, sPQ, sMu, sRs, w1, b1, w2, b2, g, bln, xo, n0, tid);
}

__global__ __launch_bounds__(256) void edge_mfma_atomic_kernel(
    const float* __restrict__ x, const float* __restrict__ e,
    const int* __restrict__ src, const int* __restrict__ dst,
    const unsigned short* __restrict__ wB1, const float* __restrict__ b1,
    const unsigned short* __restrict__ wB2, const float* __restrict__ b2,
    float* __restrict__ agg) {
  __shared__ unsigned short sIN[64 * SINB];
  __shared__ unsigned short sH[64 * SHB];
  __shared__ float sE[64 * SEB];
  const int tid = threadIdx.x;
  const int e0 = blockIdx.x * 64;
  const int lane = tid & 63;
  const int mt = tid >> 6;
  const int hl = lane >> 4;
  const int ll = lane & 15;
  {
    const int t = tid & 63, p = tid >> 6;
    int eid = e0 + t;
    int sN = src[eid], dN = dst[eid];
    const float* g0 = x + (size_t)sN * D + p * 16;
    const float* g1 = x + (size_t)dN * D + p * 16;
    const float* g2 = e + (size_t)eid * D + p * 16;
    unsigned short* row = sIN + t * SINB + p * 16;
#pragma unroll
    for (int i = 0; i < 4; ++i) {
      float4 v0 = ((const float4*)g0)[i];
      float4 v1 = ((const float4*)g1)[i];
      float4 v2 = ((const float4*)g2)[i];
      uint2 u;
      u.x = cvt2(v0.x, v0.y); u.y = cvt2(v0.z, v0.w);
      *(uint2*)(row + i * 4) = u;
      u.x = cvt2(v1.x, v1.y); u.y = cvt2(v1.z, v1.w);
      *(uint2*)(row + 64 + i * 4) = u;
      u.x = cvt2(v2.x, v2.y); u.y = cvt2(v2.z, v2.w);
      *(uint2*)(row + 128 + i * 4) = u;
      *(float4*)&sE[t * SEB + p * 16 + i * 4] = v2;
    }
  }
  __syncthreads();
  f32x4 acc[4];
#pragma unroll
  for (int nt = 0; nt < 4; ++nt) {
    float b = b1[nt * 16 + ll];
    acc[nt].x = b; acc[nt].y = b; acc[nt].z = b; acc[nt].w = b;
  }
  {
    const unsigned short* aBase = sIN + (mt * 16 + ll) * SINB + hl * 8;
#pragma unroll
    for (int kk = 0; kk < 6; ++kk) {
      bf16x8 af = *(const bf16x8*)(aBase + kk * 32);
#pragma unroll
      for (int nt = 0; nt < 4; ++nt) {
        bf16x8 bf = *(const bf16x8*)(wB1 + ((size_t)(nt * 6 + kk) * 64 + lane) * 8);
        acc[nt] = __builtin_amdgcn_mfma_f32_16x16x32_bf16(af, bf, acc[nt], 0, 0, 0);
      }
    }
  }
#pragma unroll
  for (int nt = 0; nt < 4; ++nt)
#pragma unroll
    for (int r = 0; r < 4; ++r)
      sH[(mt * 16 + hl * 4 + r) * SHB + nt * 16 + ll] = f2bf(fmaxf(acc[nt][r], 0.f));
  __syncthreads();
  f32x4 acc2[4];
#pragma unroll
  for (int nt = 0; nt < 4; ++nt) {
    float b = b2[nt * 16 + ll];
    acc2[nt].x = b; acc2[nt].y = b; acc2[nt].z = b; acc2[nt].w = b;
  }
  {
    const unsigned short* hBase = sH + (mt * 16 + ll) * SHB + hl * 8;
#pragma unroll
    for (int kk = 0; kk < 2; ++kk) {
      bf16x8 af = *(const bf16x8*)(hBase + kk * 32);
#pragma unroll
      for (int nt = 0; nt < 4; ++nt) {
        bf16x8 bf = *(const bf16x8*)(wB2 + ((size_t)(nt * 2 + kk) * 64 + lane) * 8);
        acc2[nt] = __builtin_amdgcn_mfma_f32_16x16x32_bf16(af, bf, acc2[nt], 0, 0, 0);
      }
    }
  }
#pragma unroll
  for (int r = 0; r < 4; ++r) {
    int t = mt * 16 + hl * 4 + r;
    int eid = e0 + t;
    int sN = src[eid], dN = dst[eid];
    const float* xr = x + (size_t)sN * D;
    const float* er = &sE[t * SEB];
    float* ar = agg + (size_t)dN * D;
#pragma unroll
    for (int nt = 0; nt < 4; ++nt) {
      int j = nt * 16 + ll;
      atomicAdd(ar + j, fmaxf(xr[j] + fmaf(0.5f, acc2[nt][r], er[j]), 0.f));
    }
  }
}

// ---------------- head (fallback tier only) ----------------
__global__ __launch_bounds__(256) void head_kernel(
    const float* __restrict__ x, const float* __restrict__ w,
    const float* __restrict__ b, float* __restrict__ out) {
  int nid = blockIdx.x * blockDim.x + threadIdx.x;
  if (nid >= NN) return;
  const float* xr = x + (size_t)nid * D;
  float a0 = b[0], a1 = b[1];
  for (int k = 0; k < D; ++k) {
    float v = xr[k];
    a0 = fmaf(v, w[k * 2 + 0], a0);
    a1 = fmaf(v, w[k * 2 + 1], a1);
  }
  out[nid * 2 + 0] = a0;
  out[nid * 2 + 1] = a1;
}

extern "C" void kernel_launch(void* const* d_in, const int* in_sizes, int n_in,
                              void* d_out, int out_size, void* d_ws, size_t ws_size,
                              hipStream_t stream) {
  const float* x0  = (const float*)d_in[0];
  const float* e0  = (const float*)d_in[1];
  const int*   ei  = (const int*)d_in[2];
  const float* gw1 = (const float*)d_in[3];
  const float* gb1 = (const float*)d_in[4];
  const float* gw2 = (const float*)d_in[5];
  const float* gb2 = (const float*)d_in[6];
  const float* ew1 = (const float*)d_in[7];
  const float* eb1 = (const float*)d_in[8];
  const float* ew2 = (const float*)d_in[9];
  const float* eb2 = (const float*)d_in[10];
  const float* lng = (const float*)d_in[11];
  const float* lnb = (const float*)d_in[12];
  const float* hw  = (const float*)d_in[13];
  const float* hb  = (const float*)d_in[14];
  float* out = (float*)d_out;

  char* ws = (char*)d_ws;
  const size_t SZ_X     = (size_t)NN * D * 4;             // 12.8 MB
  const size_t OFF_WB1  = 0;
  const size_t OFF_WB2  = OFF_WB1 + 24576;
  const size_t OFF_DEG  = OFF_WB2 + 8192;
  const size_t OFF_OFFS = OFF_DEG + 200704;
  const size_t OFF_CUR  = OFF_OFFS + 200704;
  const size_t OFF_BSUM = OFF_CUR + 200704;
  const size_t OFF_EPAIR= OFF_BSUM + 512;                 // 6.4 MB
  const size_t OFF_DCSR = OFF_EPAIR + (size_t)NE * 8;     // 3.2 MB
  const size_t OFF_POS  = OFF_DCSR + (size_t)NE * 4;      // 3.2 MB
  const size_t OFF_X1B  = OFF_POS + (size_t)NE * 4;       // 6.4 MB
  const size_t OFF_AGG  = OFF_X1B + (size_t)NN * D * 2;   // 12.8 MB
  const size_t OFF_ECSR = OFF_AGG + SZ_X;                 // 102.4 MB
  const size_t OFF_MSG0 = OFF_ECSR + (size_t)NE * D * 2;  // 102.4 MB
  const size_t NEED_A   = OFF_MSG0 + (size_t)NE * D * 2;  // ~237 MB
  const size_t NEED_B   = OFF_MSG0;                       // ~135 MB (no msg0)

  unsigned short* wB1 = (unsigned short*)(ws + OFF_WB1);
  unsigned short* wB2 = (unsigned short*)(ws + OFF_WB2);
  int* deg  = (int*)(ws + OFF_DEG);
  int* offs = (int*)(ws + OFF_OFFS);
  int* cur  = (int*)(ws + OFF_CUR);
  int* bsum = (int*)(ws + OFF_BSUM);
  int2* epair = (int2*)(ws + OFF_EPAIR);
  int* dcsr = (int*)(ws + OFF_DCSR);
  int* pos  = (int*)(ws + OFF_POS);
  unsigned short* x1b  = (unsigned short*)(ws + OFF_X1B);
  float* agg = (float*)(ws + OFF_AGG);
  unsigned short* ecsr = (unsigned short*)(ws + OFF_ECSR);
  unsigned short* msg0 = (unsigned short*)(ws + OFF_MSG0);

  const int* src = ei;
  const int* dst = ei + NE;

  const int nodeBlocks = (NN + 63) / 64;     // 782
  const int edgeBlocks = NE / 64;            // 12500
  const int scanBlocks = (NN + 1023) / 1024; // 49

  pack_weights_kernel<<<8, 256, 0, stream>>>(ew1, ew2, wB1, wB2);

  if (ws_size >= NEED_A) {
    // ---- CSR build (by dst) ----
    zero_int_kernel<<<(NN + 255) / 256, 256, 0, stream>>>(deg, NN);
    count_kernel<<<(NE + 255) / 256, 256, 0, stream>>>(dst, deg);
    scan_reduce_kernel<<<scanBlocks, 1024, 0, stream>>>(deg, bsum);
    scan_final_kernel<<<scanBlocks, 1024, 0, stream>>>(deg, bsum, offs, cur);
    fill_kernel<<<(NE + 255) / 256, 256, 0, stream>>>(src, dst, cur, epair, dcsr, pos);

    // ---- permute e0 into CSR order + compute layer-0 messages ----
    permute_e_kernel<<<(NE * 4 + 255) / 256, 256, 0, stream>>>(
        e0, x0, src, pos, ecsr, msg0);

    // ---- zero layer-1 agg ----
    zero_f4_kernel<<<(NN * D / 4 + 255) / 256, 256, 0, stream>>>(
        (float4*)agg, NN * D / 4);

    // ---- layer 0: streaming msg0 segment-sum + node MLP -> x1b ----
    node_mlp_g0_kernel<<<nodeBlocks, 512, 0, stream>>>(
        x0, msg0, offs, gw1, gb1, gw2, gb2, lng, lnb, x1b);

    // ---- layer-0 edge update (MFMA) + parallel segment reduce -> agg ----
    edge_mfma_seg_kernel<<<edgeBlocks, 256, 0, stream>>>(
        x1b, ecsr, epair, dcsr, wB1, eb1, wB2, eb2, agg);

    // ---- layer 1: plain node MLP (x1b + agg) + fused head ----
    node_mlp1_kernel<<<nodeBlocks, 512, 0, stream>>>(
        x1b, agg, gw1 + D * D, gb1 + D, gw2 + D * D, gb2 + D,
        lng + D, lnb + D, hw, hb, out);
  } else {
    // ---- fallback: atomic path (no CSR) ----
    float* x1f  = (float*)(ws + OFF_EPAIR);
    float* fagg = (float*)(ws + OFF_EPAIR + SZ_X);
    float* x2   = (float*)(ws + OFF_EPAIR + 2 * SZ_X);
    zero_f4_kernel<<<(NN * D / 4 + 255) / 256, 256, 0, stream>>>(
        (float4*)fagg, NN * D / 4);
    scatter_kernel<<<(NE * 16 + 255) / 256, 256, 0, stream>>>(x0, e0, src, dst, fagg);
    node_mlp_kernel<<<nodeBlocks, 256, 0, stream>>>(
        x0, fagg, gw1, gb1, gw2, gb2, lng, lnb, x1f);
    zero_f4_kernel<<<(NN * D / 4 + 255) / 256, 256, 0, stream>>>(
        (float4*)fagg, NN * D / 4);
    edge_mfma_atomic_kernel<<<edgeBlocks, 256, 0, stream>>>(
        x1f, e0, src, dst, wB1, eb1, wB2, eb2, fagg);
    node_mlp_kernel<<<nodeBlocks, 256, 0, stream>>>(
        x1f, fagg, gw1 + D * D, gb1 + D, gw2 + D * D, gb2 + D, lng + D, lnb + D, x2);
    head_kernel<<<(NN + 255) / 256, 256, 0, stream>>>(x2, hw, hb, out);
  }
}

// Round 15
// 367.840 us; speedup vs baseline: 1.1343x; 1.1343x over previous
//
#include <hip/hip_runtime.h>
#include <hip/hip_bf16.h>

#define NN 50000
#define NE 800000
#define D 64
#define K3 (3 * D)
#define LNEPS 1e-5f
#define STR 68    // f32 LDS row stride (node kernels)
#define SINB 200  // bf16 LDS row stride, edge input tile
#define SHB 72    // bf16 LDS row stride (fallback edge kernel)
#define MSTR 68   // f32 LDS row stride, msgF reduce tile
#define SEB 68    // f32 LDS row stride (fallback edge kernel)

typedef __attribute__((ext_vector_type(8))) short bf16x8;
typedef __attribute__((ext_vector_type(4))) float f32x4;

// hardware bf16 conversions (RNE)
__device__ __forceinline__ unsigned cvt2(float lo, float hi) {
  __hip_bfloat162 h = __float22bfloat162_rn(make_float2(lo, hi));
  return *(unsigned*)&h;
}
__device__ __forceinline__ unsigned short f2bf(float f) {
  __hip_bfloat16 h = __float2bfloat16(f);
  return *(unsigned short*)&h;
}
__device__ __forceinline__ float bf2f(unsigned short s) {
  return __uint_as_float((unsigned)s << 16);
}

#define FMA4x4(v, w)                                                  \
  a0.x = fmaf(v.x, w.x, a0.x); a0.y = fmaf(v.x, w.y, a0.y);           \
  a0.z = fmaf(v.x, w.z, a0.z); a0.w = fmaf(v.x, w.w, a0.w);           \
  a1.x = fmaf(v.y, w.x, a1.x); a1.y = fmaf(v.y, w.y, a1.y);           \
  a1.z = fmaf(v.y, w.z, a1.z); a1.w = fmaf(v.y, w.w, a1.w);           \
  a2.x = fmaf(v.z, w.x, a2.x); a2.y = fmaf(v.z, w.y, a2.y);           \
  a2.z = fmaf(v.z, w.z, a2.z); a2.w = fmaf(v.z, w.w, a2.w);           \
  a3.x = fmaf(v.w, w.x, a3.x); a3.y = fmaf(v.w, w.y, a3.y);           \
  a3.z = fmaf(v.w, w.z, a3.z); a3.w = fmaf(v.w, w.w, a3.w);

#define FMA2x4(v, w)                                                  \
  a0.x = fmaf(v.x, w.x, a0.x); a0.y = fmaf(v.x, w.y, a0.y);           \
  a0.z = fmaf(v.x, w.z, a0.z); a0.w = fmaf(v.x, w.w, a0.w);           \
  a1.x = fmaf(v.y, w.x, a1.x); a1.y = fmaf(v.y, w.y, a1.y);           \
  a1.z = fmaf(v.y, w.z, a1.z); a1.w = fmaf(v.y, w.w, a1.w);

#define HSTORE_RELU(buf)                                              \
  buf[(j0+0)*STR + t0+0] = fmaxf(a0.x, 0.f);                          \
  buf[(j0+1)*STR + t0+0] = fmaxf(a0.y, 0.f);                          \
  buf[(j0+2)*STR + t0+0] = fmaxf(a0.z, 0.f);                          \
  buf[(j0+3)*STR + t0+0] = fmaxf(a0.w, 0.f);                          \
  buf[(j0+0)*STR + t0+1] = fmaxf(a1.x, 0.f);                          \
  buf[(j0+1)*STR + t0+1] = fmaxf(a1.y, 0.f);                          \
  buf[(j0+2)*STR + t0+1] = fmaxf(a1.z, 0.f);                          \
  buf[(j0+3)*STR + t0+1] = fmaxf(a1.w, 0.f);                          \
  buf[(j0+0)*STR + t0+2] = fmaxf(a2.x, 0.f);                          \
  buf[(j0+1)*STR + t0+2] = fmaxf(a2.y, 0.f);                          \
  buf[(j0+2)*STR + t0+2] = fmaxf(a2.z, 0.f);                          \
  buf[(j0+3)*STR + t0+2] = fmaxf(a2.w, 0.f);                          \
  buf[(j0+0)*STR + t0+3] = fmaxf(a3.x, 0.f);                          \
  buf[(j0+1)*STR + t0+3] = fmaxf(a3.y, 0.f);                          \
  buf[(j0+2)*STR + t0+3] = fmaxf(a3.z, 0.f);                          \
  buf[(j0+3)*STR + t0+3] = fmaxf(a3.w, 0.f);

// ---------------- zero kernels ----------------
__global__ __launch_bounds__(256) void zero_int_kernel(int* __restrict__ p, int n) {
  int i = blockIdx.x * 256 + threadIdx.x;
  if (i < n) p[i] = 0;
}
__global__ __launch_bounds__(256) void zero_f4_kernel(float4* __restrict__ p, int n) {
  int i = blockIdx.x * 256 + threadIdx.x;
  if (i < n) p[i] = make_float4(0.f, 0.f, 0.f, 0.f);
}

// ---------------- CSR build ----------------
__global__ __launch_bounds__(256) void count_kernel(
    const int* __restrict__ dst, int* __restrict__ deg) {
  int e = blockIdx.x * 256 + threadIdx.x;
  if (e < NE) atomicAdd(&deg[dst[e]], 1);
}

__global__ __launch_bounds__(1024) void scan_reduce_kernel(
    const int* __restrict__ deg, int* __restrict__ bsum) {
  __shared__ int sS[16];
  int i = blockIdx.x * 1024 + threadIdx.x;
  int v = (i < NN) ? deg[i] : 0;
#pragma unroll
  for (int o = 32; o > 0; o >>= 1) v += __shfl_down(v, o, 64);
  if ((threadIdx.x & 63) == 0) sS[threadIdx.x >> 6] = v;
  __syncthreads();
  if (threadIdx.x == 0) {
    int s = 0;
#pragma unroll
    for (int k = 0; k < 16; ++k) s += sS[k];
    bsum[blockIdx.x] = s;
  }
}

__global__ __launch_bounds__(1024) void scan_final_kernel(
    const int* __restrict__ deg, const int* __restrict__ bsum,
    int* __restrict__ off, int* __restrict__ cur) {
  __shared__ int sD[1024];
  __shared__ int sOfs;
  const int t = threadIdx.x;
  const int b = blockIdx.x;
  int i = b * 1024 + t;
  int v = (i < NN) ? deg[i] : 0;
  sD[t] = v;
  if (t == 0) {
    int o = 0;
    for (int k = 0; k < b; ++k) o += bsum[k];
    sOfs = o;
  }
  __syncthreads();
  for (int st = 1; st < 1024; st <<= 1) {
    int add = (t >= st) ? sD[t - st] : 0;
    __syncthreads();
    sD[t] += add;
    __syncthreads();
  }
  if (i < NN) {
    int excl = sOfs + sD[t] - v;
    off[i] = excl;
    cur[i] = excl;
    if (i == NN - 1) off[NN] = NE;
  }
}

// epair[p] = {eid, src[eid]}, dcsr[p] = dst[eid], pos[eid] = p
__global__ __launch_bounds__(256) void fill_kernel(
    const int* __restrict__ src, const int* __restrict__ dst,
    int* __restrict__ cur, int2* __restrict__ epair,
    int* __restrict__ dcsr, int* __restrict__ pos) {
  int e = blockIdx.x * 256 + threadIdx.x;
  if (e < NE) {
    int d = dst[e];
    int p = atomicAdd(&cur[d], 1);
    epair[p] = make_int2(e, src[e]);
    dcsr[p] = d;
    pos[e] = p;
  }
}

// ---------------- permute e0 into CSR order as bf16 ----------------
__global__ __launch_bounds__(256) void permute_e_kernel(
    const float* __restrict__ e, const int* __restrict__ pos,
    unsigned short* __restrict__ ecsr) {
  int tid = blockIdx.x * 256 + threadIdx.x;  // NE*4 threads
  int eid = tid >> 2, q = tid & 3;
  if (eid >= NE) return;
  int p = pos[eid];
  const float4* srcp = (const float4*)(e + (size_t)eid * D + q * 16);
  float4 v0 = srcp[0], v1 = srcp[1], v2 = srcp[2], v3 = srcp[3];
  uint4 u0, u1;
  u0.x = cvt2(v0.x, v0.y); u0.y = cvt2(v0.z, v0.w);
  u0.z = cvt2(v1.x, v1.y); u0.w = cvt2(v1.z, v1.w);
  u1.x = cvt2(v2.x, v2.y); u1.y = cvt2(v2.z, v2.w);
  u1.z = cvt2(v3.x, v3.y); u1.w = cvt2(v3.z, v3.w);
  uint4* dstp = (uint4*)(ecsr + (size_t)p * D + q * 16);
  dstp[0] = u0;
  dstp[1] = u1;
}

// ---------------- pack edge-MLP weights ----------------
__global__ __launch_bounds__(256) void pack_weights_kernel(
    const float* __restrict__ w1, const float* __restrict__ w2,
    unsigned short* __restrict__ wB1, unsigned short* __restrict__ wB2) {
  int tid = blockIdx.x * 256 + threadIdx.x;
  const float* wsrc;
  unsigned short* wdst;
  int kb, j, slot;
  if (tid < 1536) {
    int nt = tid / 384, kk = (tid / 64) % 6, l = tid & 63;
    kb = kk * 32 + (l >> 4) * 8;
    j = nt * 16 + (l & 15);
    wsrc = w1; wdst = wB1; slot = tid;
  } else {
    int t = tid - 1536;
    int nt = t / 128, kk = (t / 64) & 1, l = t & 63;
    kb = kk * 32 + (l >> 4) * 8;
    j = nt * 16 + (l & 15);
    wsrc = w2; wdst = wB2; slot = t;
  }
  unsigned short b[8];
#pragma unroll
  for (int i = 0; i < 8; ++i) b[i] = f2bf(wsrc[(kb + i) * D + j]);
  uint4 v;
  v.x = (unsigned)b[0] | ((unsigned)b[1] << 16);
  v.y = (unsigned)b[2] | ((unsigned)b[3] << 16);
  v.z = (unsigned)b[4] | ((unsigned)b[5] << 16);
  v.w = (unsigned)b[6] | ((unsigned)b[7] << 16);
  *(uint4*)(wdst + (size_t)slot * 8) = v;
}

// ---------------- 512-thread MLP tail ----------------
__device__ __forceinline__ void mlp_tail512(
    float* sIN, float* sH, float* sPS, float* sPQ, float* sMu, float* sRs,
    const float* __restrict__ w1, const float* __restrict__ b1,
    const float* __restrict__ w2, const float* __restrict__ b2,
    const float* __restrict__ g, const float* __restrict__ bln,
    float* __restrict__ xo, unsigned short* __restrict__ xob,
    const float* __restrict__ hw, const float* __restrict__ hb,
    float* __restrict__ outh,
    int n0, int tid) {
  __syncthreads();
  const int tj = tid & 15, tt = tid >> 4;   // 16 x 32
  const int j0 = tj * 4, t0 = tt * 2;
  float4 a0, a1;

  {
    float4 bv = *(const float4*)(b1 + j0);
    a0 = a1 = bv;
    for (int k = 0; k < D; ++k) {
      float4 w = *(const float4*)(w1 + k * D + j0);
      float2 v = *(const float2*)&sIN[k * STR + t0];
      FMA2x4(v, w)
    }
  }
  sH[(j0 + 0) * STR + t0 + 0] = fmaxf(a0.x, 0.f);
  sH[(j0 + 1) * STR + t0 + 0] = fmaxf(a0.y, 0.f);
  sH[(j0 + 2) * STR + t0 + 0] = fmaxf(a0.z, 0.f);
  sH[(j0 + 3) * STR + t0 + 0] = fmaxf(a0.w, 0.f);
  sH[(j0 + 0) * STR + t0 + 1] = fmaxf(a1.x, 0.f);
  sH[(j0 + 1) * STR + t0 + 1] = fmaxf(a1.y, 0.f);
  sH[(j0 + 2) * STR + t0 + 1] = fmaxf(a1.z, 0.f);
  sH[(j0 + 3) * STR + t0 + 1] = fmaxf(a1.w, 0.f);
  __syncthreads();

  {
    float4 bv = *(const float4*)(b2 + j0);
    a0 = a1 = bv;
    for (int k = 0; k < D; ++k) {
      float4 w = *(const float4*)(w2 + k * D + j0);
      float2 v = *(const float2*)&sH[k * STR + t0];
      FMA2x4(v, w)
    }
  }
  __syncthreads();
  *(float4*)&sH[(t0 + 0) * STR + j0] = a0;
  *(float4*)&sH[(t0 + 1) * STR + j0] = a1;
  __syncthreads();

  {
    const int t = tid & 63, p = tid >> 6;
    const float* r = &sH[t * STR + p * 8];
    float s = 0.f, q = 0.f;
#pragma unroll
    for (int i = 0; i < 8; ++i) { float v = r[i]; s += v; q = fmaf(v, v, q); }
    sPS[p * 64 + t] = s;
    sPQ[p * 64 + t] = q;
  }
  __syncthreads();
  if (tid < 64) {
    float s = 0.f, q = 0.f;
#pragma unroll
    for (int p = 0; p < 8; ++p) { s += sPS[p * 64 + tid]; q += sPQ[p * 64 + tid]; }
    float mu = s * (1.f / 64.f);
    float var = q * (1.f / 64.f) - mu * mu;
    sMu[tid] = mu;
    sRs[tid] = rsqrtf(var + LNEPS);
  }
  __syncthreads();

  {
    const int t = tid >> 3, c = (tid & 7) * 8;
    int node = n0 + t;
    if (node < NN) {
      float mu = sMu[t], rs = sRs[t];
      float4 v0 = *(const float4*)&sH[t * STR + c + 0];
      float4 v1 = *(const float4*)&sH[t * STR + c + 4];
      float4 g0v = *(const float4*)(g + c + 0);
      float4 g1v = *(const float4*)(g + c + 4);
      float4 b0v = *(const float4*)(bln + c + 0);
      float4 b1v = *(const float4*)(bln + c + 4);
      float4 r0, r1;
      r0.x = fmaxf(fmaf((v0.x - mu) * rs, g0v.x, b0v.x), 0.f);
      r0.y = fmaxf(fmaf((v0.y - mu) * rs, g0v.y, b0v.y), 0.f);
      r0.z = fmaxf(fmaf((v0.z - mu) * rs, g0v.z, b0v.z), 0.f);
      r0.w = fmaxf(fmaf((v0.w - mu) * rs, g0v.w, b0v.w), 0.f);
      r1.x = fmaxf(fmaf((v1.x - mu) * rs, g1v.x, b1v.x), 0.f);
      r1.y = fmaxf(fmaf((v1.y - mu) * rs, g1v.y, b1v.y), 0.f);
      r1.z = fmaxf(fmaf((v1.z - mu) * rs, g1v.z, b1v.z), 0.f);
      r1.w = fmaxf(fmaf((v1.w - mu) * rs, g1v.w, b1v.w), 0.f);
      if (outh) {
        float h0, h1;
        h0 = r0.x * hw[(c + 0) * 2 + 0] + r0.y * hw[(c + 1) * 2 + 0] +
             r0.z * hw[(c + 2) * 2 + 0] + r0.w * hw[(c + 3) * 2 + 0] +
             r1.x * hw[(c + 4) * 2 + 0] + r1.y * hw[(c + 5) * 2 + 0] +
             r1.z * hw[(c + 6) * 2 + 0] + r1.w * hw[(c + 7) * 2 + 0];
        h1 = r0.x * hw[(c + 0) * 2 + 1] + r0.y * hw[(c + 1) * 2 + 1] +
             r0.z * hw[(c + 2) * 2 + 1] + r0.w * hw[(c + 3) * 2 + 1] +
             r1.x * hw[(c + 4) * 2 + 1] + r1.y * hw[(c + 5) * 2 + 1] +
             r1.z * hw[(c + 6) * 2 + 1] + r1.w * hw[(c + 7) * 2 + 1];
#pragma unroll
        for (int o = 1; o < 8; o <<= 1) {
          h0 += __shfl_xor(h0, o, 64);
          h1 += __shfl_xor(h1, o, 64);
        }
        if ((tid & 7) == 0) {
          outh[node * 2 + 0] = h0 + hb[0];
          outh[node * 2 + 1] = h1 + hb[1];
        }
      } else {
        if (xo) {
          float* o = xo + (size_t)node * D + c;
          ((float4*)o)[0] = r0;
          ((float4*)o)[1] = r1;
        }
        if (xob) {
          uint4 u;
          u.x = cvt2(r0.x, r0.y); u.y = cvt2(r0.z, r0.w);
          u.z = cvt2(r1.x, r1.y); u.w = cvt2(r1.z, r1.w);
          *(uint4*)(xob + (size_t)node * D + c) = u;
        }
      }
    }
  }
}

// ---------------- layer-0: fused CSR gather (ecsr stream + cached x) + node MLP -> x1b ----------------
__global__ __launch_bounds__(512) void node_mlp_g0_kernel(
    const float* __restrict__ x, const unsigned short* __restrict__ ecsr,
    const int2* __restrict__ epair, const int* __restrict__ off,
    const float* __restrict__ w1, const float* __restrict__ b1,
    const float* __restrict__ w2, const float* __restrict__ b2,
    const float* __restrict__ g, const float* __restrict__ bln,
    unsigned short* __restrict__ xob) {
  __shared__ float sIN[D * STR];
  __shared__ float sH[D * STR];
  __shared__ float sPS[512], sPQ[512], sMu[64], sRs[64];
  const int tid = threadIdx.x;
  const int n0 = blockIdx.x * 64;
  const int wv = tid >> 6, lane = tid & 63;
  for (int q = 0; q < 8; ++q) {
    int t = wv * 8 + q;
    int node = n0 + t;
    float acc = 0.f;
    if (node < NN) {
      acc = x[(size_t)node * D + lane];  // self term
      int beg = off[node], end = off[node + 1];
      const unsigned short* er = ecsr + (size_t)beg * D + lane;
      int cnt = end - beg, i = 0;
      for (; i + 3 < cnt; i += 4) {
        int s0 = epair[beg + i + 0].y, s1 = epair[beg + i + 1].y;
        int s2 = epair[beg + i + 2].y, s3 = epair[beg + i + 3].y;
        float xa = x[(size_t)s0 * D + lane], ea = bf2f(er[(size_t)(i + 0) * D]);
        float xb = x[(size_t)s1 * D + lane], eb = bf2f(er[(size_t)(i + 1) * D]);
        float xc = x[(size_t)s2 * D + lane], ec = bf2f(er[(size_t)(i + 2) * D]);
        float xd = x[(size_t)s3 * D + lane], ed = bf2f(er[(size_t)(i + 3) * D]);
        acc += (fmaxf(xa + ea, 0.f) + fmaxf(xb + eb, 0.f)) +
               (fmaxf(xc + ec, 0.f) + fmaxf(xd + ed, 0.f));
      }
      for (; i < cnt; ++i) {
        int s0 = epair[beg + i].y;
        acc += fmaxf(x[(size_t)s0 * D + lane] + bf2f(er[(size_t)i * D]), 0.f);
      }
    }
    sIN[lane * STR + t] = acc;
  }
  mlp_tail512(sIN, sH, sPS, sPQ, sMu, sRs, w1, b1, w2, b2, g, bln,
              nullptr, xob, nullptr, nullptr, nullptr, n0, tid);
}

// ---------------- layer-1: plain node MLP (x1b + agg) + fused head ----------------
__global__ __launch_bounds__(512) void node_mlp1_kernel(
    const unsigned short* __restrict__ xb, const float* __restrict__ agg,
    const float* __restrict__ w1, const float* __restrict__ b1,
    const float* __restrict__ w2, const float* __restrict__ b2,
    const float* __restrict__ g, const float* __restrict__ bln,
    const float* __restrict__ hw, const float* __restrict__ hb,
    float* __restrict__ outh) {
  __shared__ float sIN[D * STR];
  __shared__ float sH[D * STR];
  __shared__ float sPS[512], sPQ[512], sMu[64], sRs[64];
  const int tid = threadIdx.x;
  const int n0 = blockIdx.x * 64;
  {
    const int t = tid & 63, p = tid >> 6;  // 8 feats each
    int node = n0 + t;
    int cn = node < NN ? node : 0;
    const unsigned short* xr = xb + (size_t)cn * D + p * 8;
    const float* ar = agg + (size_t)cn * D + p * 8;
    uint4 xv = *(const uint4*)xr;
    float4 a0v = ((const float4*)ar)[0];
    float4 a1v = ((const float4*)ar)[1];
    int k = p * 8;
    sIN[(k + 0) * STR + t] = bf2f((unsigned short)(xv.x & 0xFFFF)) + a0v.x;
    sIN[(k + 1) * STR + t] = bf2f((unsigned short)(xv.x >> 16)) + a0v.y;
    sIN[(k + 2) * STR + t] = bf2f((unsigned short)(xv.y & 0xFFFF)) + a0v.z;
    sIN[(k + 3) * STR + t] = bf2f((unsigned short)(xv.y >> 16)) + a0v.w;
    sIN[(k + 4) * STR + t] = bf2f((unsigned short)(xv.z & 0xFFFF)) + a1v.x;
    sIN[(k + 5) * STR + t] = bf2f((unsigned short)(xv.z >> 16)) + a1v.y;
    sIN[(k + 6) * STR + t] = bf2f((unsigned short)(xv.w & 0xFFFF)) + a1v.z;
    sIN[(k + 7) * STR + t] = bf2f((unsigned short)(xv.w >> 16)) + a1v.w;
  }
  mlp_tail512(sIN, sH, sPS, sPQ, sMu, sRs, w1, b1, w2, b2, g, bln,
              nullptr, nullptr, hw, hb, outh, n0, tid);
}

// ---------------- MFMA edge MLP + parallel in-LDS segment reduce -> agg atomics ----------------
// LDS: single sIN buffer; GEMM2's A-operand aliases the dead x[dst] columns (64..127).
__global__ __launch_bounds__(256) void edge_mfma_seg_kernel(
    const unsigned short* __restrict__ x1b, const unsigned short* __restrict__ ecsr,
    const int2* __restrict__ epair, const int* __restrict__ dcsr,
    const unsigned short* __restrict__ wB1, const float* __restrict__ b1,
    const unsigned short* __restrict__ wB2, const float* __restrict__ b2,
    float* __restrict__ agg) {
  __shared__ unsigned short sIN[64 * SINB];  // 25600 B; cols 64..127 reused for relu(h);
                                             // whole buffer reused as f32 msgF[64][MSTR]
  __shared__ int sDst[64];

  const int tid = threadIdx.x;
  const int e0 = blockIdx.x * 64;  // CSR slot base
  const int lane = tid & 63;
  const int mt = tid >> 6;
  const int hl = lane >> 4;
  const int ll = lane & 15;

  // ---- stage: pure 16B copies
  {
    const int t = tid & 63, p = tid >> 6;
    int slot = e0 + t;
    int sN = epair[slot].y;
    int dN = dcsr[slot];
    if (p == 0) sDst[t] = dN;
    const uint4* xs = (const uint4*)(x1b + (size_t)sN * D + p * 16);
    const uint4* xd = (const uint4*)(x1b + (size_t)dN * D + p * 16);
    const uint4* ec = (const uint4*)(ecsr + (size_t)slot * D + p * 16);
    uint4* r0 = (uint4*)(sIN + t * SINB + p * 16);
    uint4* r1 = (uint4*)(sIN + t * SINB + 64 + p * 16);
    uint4* r2 = (uint4*)(sIN + t * SINB + 128 + p * 16);
    uint4 a0v = xs[0], a1v = xs[1];
    uint4 b0v = xd[0], b1v = xd[1];
    uint4 c0v = ec[0], c1v = ec[1];
    r0[0] = a0v; r0[1] = a1v;
    r1[0] = b0v; r1[1] = b1v;
    r2[0] = c0v; r2[1] = c1v;
  }
  __syncthreads();

  // ---- GEMM1 (K=192): reads sIN cols 0..191
  f32x4 acc[4];
#pragma unroll
  for (int nt = 0; nt < 4; ++nt) {
    float b = b1[nt * 16 + ll];
    acc[nt].x = b; acc[nt].y = b; acc[nt].z = b; acc[nt].w = b;
  }
  {
    const unsigned short* aBase = sIN + (mt * 16 + ll) * SINB + hl * 8;
#pragma unroll
    for (int kk = 0; kk < 6; ++kk) {
      bf16x8 af = *(const bf16x8*)(aBase + kk * 32);
#pragma unroll
      for (int nt = 0; nt < 4; ++nt) {
        bf16x8 bf = *(const bf16x8*)(wB1 + ((size_t)(nt * 6 + kk) * 64 + lane) * 8);
        acc[nt] = __builtin_amdgcn_mfma_f32_16x16x32_bf16(af, bf, acc[nt], 0, 0, 0);
      }
    }
  }
  __syncthreads();  // all GEMM1 reads done; cols 64..127 now dead -> reuse for relu(h)

#pragma unroll
  for (int nt = 0; nt < 4; ++nt)
#pragma unroll
    for (int r = 0; r < 4; ++r)
      sIN[(mt * 16 + hl * 4 + r) * SINB + 64 + nt * 16 + ll] =
          f2bf(fmaxf(acc[nt][r], 0.f));
  __syncthreads();

  // ---- GEMM2 (K=64): A from aliased cols 64..127
  f32x4 acc2[4];
#pragma unroll
  for (int nt = 0; nt < 4; ++nt) {
    float b = b2[nt * 16 + ll];
    acc2[nt].x = b; acc2[nt].y = b; acc2[nt].z = b; acc2[nt].w = b;
  }
  {
    const unsigned short* hBase = sIN + (mt * 16 + ll) * SINB + 64 + hl * 8;
#pragma unroll
    for (int kk = 0; kk < 2; ++kk) {
      bf16x8 af = *(const bf16x8*)(hBase + kk * 32);
#pragma unroll
      for (int nt = 0; nt < 4; ++nt) {
        bf16x8 bf = *(const bf16x8*)(wB2 + ((size_t)(nt * 2 + kk) * 64 + lane) * 8);
        acc2[nt] = __builtin_amdgcn_mfma_f32_16x16x32_bf16(af, bf, acc2[nt], 0, 0, 0);
      }
    }
  }

  // ---- msg in registers: relu(x[src] + e + 0.5*o)  (cols 0..63 and 128..191 intact)
  float m0x, m0y, m0z, m0w, m1x, m1y, m1z, m1w;
  float m2x, m2y, m2z, m2w, m3x, m3y, m3z, m3w;
  {
    const unsigned short* x0r = sIN + (mt * 16 + hl * 4 + 0) * SINB;
    const unsigned short* x1r = sIN + (mt * 16 + hl * 4 + 1) * SINB;
    const unsigned short* x2r = sIN + (mt * 16 + hl * 4 + 2) * SINB;
    const unsigned short* x3r = sIN + (mt * 16 + hl * 4 + 3) * SINB;
#define MSG(xr, nt, r) fmaxf(bf2f(xr[nt * 16 + ll]) + fmaf(0.5f, acc2[nt][r], bf2f(xr[128 + nt * 16 + ll])), 0.f)
    m0x = MSG(x0r, 0, 0); m0y = MSG(x0r, 1, 0); m0z = MSG(x0r, 2, 0); m0w = MSG(x0r, 3, 0);
    m1x = MSG(x1r, 0, 1); m1y = MSG(x1r, 1, 1); m1z = MSG(x1r, 2, 1); m1w = MSG(x1r, 3, 1);
    m2x = MSG(x2r, 0, 2); m2y = MSG(x2r, 1, 2); m2z = MSG(x2r, 2, 2); m2w = MSG(x2r, 3, 2);
    m3x = MSG(x3r, 0, 3); m3y = MSG(x3r, 1, 3); m3z = MSG(x3r, 2, 3); m3w = MSG(x3r, 3, 3);
#undef MSG
  }
  __syncthreads();  // all sIN reads done; reuse as f32 msgF

  float* msgF = (float*)sIN;  // [64][MSTR], 17408 B
  {
    int tb = mt * 16 + hl * 4;
    msgF[(tb + 0) * MSTR + 0 * 16 + ll] = m0x;
    msgF[(tb + 0) * MSTR + 1 * 16 + ll] = m0y;
    msgF[(tb + 0) * MSTR + 2 * 16 + ll] = m0z;
    msgF[(tb + 0) * MSTR + 3 * 16 + ll] = m0w;
    msgF[(tb + 1) * MSTR + 0 * 16 + ll] = m1x;
    msgF[(tb + 1) * MSTR + 1 * 16 + ll] = m1y;
    msgF[(tb + 1) * MSTR + 2 * 16 + ll] = m1z;
    msgF[(tb + 1) * MSTR + 3 * 16 + ll] = m1w;
    msgF[(tb + 2) * MSTR + 0 * 16 + ll] = m2x;
    msgF[(tb + 2) * MSTR + 1 * 16 + ll] = m2y;
    msgF[(tb + 2) * MSTR + 2 * 16 + ll] = m2z;
    msgF[(tb + 2) * MSTR + 3 * 16 + ll] = m2w;
    msgF[(tb + 3) * MSTR + 0 * 16 + ll] = m3x;
    msgF[(tb + 3) * MSTR + 1 * 16 + ll] = m3y;
    msgF[(tb + 3) * MSTR + 2 * 16 + ll] = m3z;
    msgF[(tb + 3) * MSTR + 3 * 16 + ll] = m3w;
  }
  __syncthreads();

  // ---- parallel segment reduce: thread (p, j) walks 16 rows of column j
  {
    const int p = tid >> 6, j = tid & 63;
    const int rbeg = p * 16, rend = rbeg + 16;
    int cur = sDst[rbeg];
    float sum = msgF[rbeg * MSTR + j];
    for (int t = rbeg + 1; t < rend; ++t) {
      int d = sDst[t];
      float v = msgF[t * MSTR + j];
      if (d != cur) {
        atomicAdd(&agg[(size_t)cur * D + j], sum);
        cur = d;
        sum = v;
      } else {
        sum += v;
      }
    }
    atomicAdd(&agg[(size_t)cur * D + j], sum);
  }
}

// ---------------- legacy kernels (fallback tier) ----------------
__global__ __launch_bounds__(256) void scatter_kernel(
    const float* __restrict__ x, const float* __restrict__ e,
    const int* __restrict__ src, const int* __restrict__ dst,
    float* __restrict__ agg) {
  int tid = blockIdx.x * blockDim.x + threadIdx.x;
  if (tid >= NE * 16) return;
  int eid = tid >> 4, q = tid & 15;
  int s = src[eid], d = dst[eid];
  float4 xv = ((const float4*)(x + (size_t)s * D))[q];
  float4 ev = ((const float4*)(e + (size_t)eid * D))[q];
  float* a = agg + (size_t)d * D + q * 4;
  atomicAdd(a + 0, fmaxf(xv.x + ev.x, 0.f));
  atomicAdd(a + 1, fmaxf(xv.y + ev.y, 0.f));
  atomicAdd(a + 2, fmaxf(xv.z + ev.z, 0.f));
  atomicAdd(a + 3, fmaxf(xv.w + ev.w, 0.f));
}

__device__ __forceinline__ void mlp_tail256(
    float* sIN, float* sH, float* sPS, float* sPQ, float* sMu, float* sRs,
    const float* __restrict__ w1, const float* __restrict__ b1,
    const float* __restrict__ w2, const float* __restrict__ b2,
    const float* __restrict__ g, const float* __restrict__ bln,
    float* __restrict__ xo, int n0, int tid) {
  __syncthreads();
  const int tj = tid & 15, tt = tid >> 4;
  const int j0 = tj * 4, t0 = tt * 4;
  float4 a0, a1, a2, a3;
  {
    float4 bv = *(const float4*)(b1 + j0);
    a0 = a1 = a2 = a3 = bv;
    for (int k = 0; k < D; ++k) {
      float4 w = *(const float4*)(w1 + k * D + j0);
      float4 v = *(const float4*)&sIN[k * STR + t0];
      FMA4x4(v, w)
    }
  }
  HSTORE_RELU(sH)
  __syncthreads();
  {
    float4 bv = *(const float4*)(b2 + j0);
    a0 = a1 = a2 = a3 = bv;
    for (int k = 0; k < D; ++k) {
      float4 w = *(const float4*)(w2 + k * D + j0);
      float4 v = *(const float4*)&sH[k * STR + t0];
      FMA4x4(v, w)
    }
  }
  __syncthreads();
  *(float4*)&sH[(t0 + 0) * STR + j0] = a0;
  *(float4*)&sH[(t0 + 1) * STR + j0] = a1;
  *(float4*)&sH[(t0 + 2) * STR + j0] = a2;
  *(float4*)&sH[(t0 + 3) * STR + j0] = a3;
  __syncthreads();
  {
    const int t = tid & 63, p = tid >> 6;
    const float* r = &sH[t * STR + p * 16];
    float s = 0.f, q = 0.f;
#pragma unroll
    for (int i = 0; i < 16; ++i) { float v = r[i]; s += v; q = fmaf(v, v, q); }
    sPS[p * 64 + t] = s;
    sPQ[p * 64 + t] = q;
  }
  __syncthreads();
  if (tid < 64) {
    float s = sPS[tid] + sPS[64 + tid] + sPS[128 + tid] + sPS[192 + tid];
    float q = sPQ[tid] + sPQ[64 + tid] + sPQ[128 + tid] + sPQ[192 + tid];
    float mu = s * (1.f / 64.f);
    float var = q * (1.f / 64.f) - mu * mu;
    sMu[tid] = mu;
    sRs[tid] = rsqrtf(var + LNEPS);
  }
  __syncthreads();
  {
    const int t = tid >> 2, c = (tid & 3) * 16;
    int node = n0 + t;
    if (node < NN) {
      float mu = sMu[t], rs = sRs[t];
      float* o = xo + (size_t)node * D + c;
#pragma unroll
      for (int i = 0; i < 4; ++i) {
        float4 v = *(const float4*)&sH[t * STR + c + i * 4];
        float4 gv = *(const float4*)(g + c + i * 4);
        float4 bv = *(const float4*)(bln + c + i * 4);
        float4 r;
        r.x = fmaxf(fmaf((v.x - mu) * rs, gv.x, bv.x), 0.f);
        r.y = fmaxf(fmaf((v.y - mu) * rs, gv.y, bv.y), 0.f);
        r.z = fmaxf(fmaf((v.z - mu) * rs, gv.z, bv.z), 0.f);
        r.w = fmaxf(fmaf((v.w - mu) * rs, gv.w, bv.w), 0.f);
        ((float4*)o)[i] = r;
      }
    }
  }
}

__global__ __launch_bounds__(256) void node_mlp_kernel(
    const float* __restrict__ x, const float* __restrict__ agg,
    const float* __restrict__ w1, const float* __restrict__ b1,
    const float* __restrict__ w2, const float* __restrict__ b2,
    const float* __restrict__ g, const float* __restrict__ bln,
    float* __restrict__ xo) {
  __shared__ float sIN[D * STR];
  __shared__ float sH[D * STR];
  __shared__ float sPS[256], sPQ[256], sMu[64], sRs[64];
  const int tid = threadIdx.x;
  const int n0 = blockIdx.x * 64;
  {
    const int t = tid & 63, p = tid >> 6;
    int node = n0 + t;
    int cn = node < NN ? node : 0;
    const float* xr = x + (size_t)cn * D + p * 16;
    const float* ar = agg + (size_t)cn * D + p * 16;
#pragma unroll
    for (int i = 0; i < 4; ++i) {
      float4 xv = ((const float4*)xr)[i];
      float4 av = ((const float4*)ar)[i];
      int k = p * 16 + i * 4;
      sIN[(k + 0) * STR + t] = xv.x + av.x;
      sIN[(k + 1) * STR + t] = xv.y + av.y;
      sIN[(k + 2) * STR + t] = xv.z + av.z;
      sIN[(k + 3) * STR + t] = xv.w + av.w;
    }
  }
  mlp_tail256(sIN, sH, sPS, sPQ, sMu, sRs, w1, b1, w2, b2, g, bln, xo, n0, tid);
}

__global__ __launch_bounds__(256) void edge_mfma_atomic_kernel(
    const float* __restrict__ x, const float* __restrict__ e,
    const int* __restrict__ src, const int* __restrict__ dst,
    const unsigned short* __restrict__ wB1, const float* __restrict__ b1,
    const unsigned short* __restrict__ wB2, const float* __restrict__ b2,
    float* __restrict__ agg) {
  __shared__ unsigned short sIN[64 * SINB];
  __shared__ unsigned short sH[64 * SHB];
  __shared__ float sE[64 * SEB];
  const int tid = threadIdx.x;
  const int e0 = blockIdx.x * 64;
  const int lane = tid & 63;
  const int mt = tid >> 6;
  const int hl = lane >> 4;
  const int ll = lane & 15;
  {
    const int t = tid & 63, p = tid >> 6;
    int eid = e0 + t;
    int sN = src[eid], dN = dst[eid];
    const float* g0 = x + (size_t)sN * D + p * 16;
    const float* g1 = x + (size_t)dN * D + p * 16;
    const float* g2 = e + (size_t)eid * D + p * 16;
    unsigned short* row = sIN + t * SINB + p * 16;
#pragma unroll
    for (int i = 0; i < 4; ++i) {
      float4 v0 = ((const float4*)g0)[i];
      float4 v1 = ((const float4*)g1)[i];
      float4 v2 = ((const float4*)g2)[i];
      uint2 u;
      u.x = cvt2(v0.x, v0.y); u.y = cvt2(v0.z, v0.w);
      *(uint2*)(row + i * 4) = u;
      u.x = cvt2(v1.x, v1.y); u.y = cvt2(v1.z, v1.w);
      *(uint2*)(row + 64 + i * 4) = u;
      u.x = cvt2(v2.x, v2.y); u.y = cvt2(v2.z, v2.w);
      *(uint2*)(row + 128 + i * 4) = u;
      *(float4*)&sE[t * SEB + p * 16 + i * 4] = v2;
    }
  }
  __syncthreads();
  f32x4 acc[4];
#pragma unroll
  for (int nt = 0; nt < 4; ++nt) {
    float b = b1[nt * 16 + ll];
    acc[nt].x = b; acc[nt].y = b; acc[nt].z = b; acc[nt].w = b;
  }
  {
    const unsigned short* aBase = sIN + (mt * 16 + ll) * SINB + hl * 8;
#pragma unroll
    for (int kk = 0; kk < 6; ++kk) {
      bf16x8 af = *(const bf16x8*)(aBase + kk * 32);
#pragma unroll
      for (int nt = 0; nt < 4; ++nt) {
        bf16x8 bf = *(const bf16x8*)(wB1 + ((size_t)(nt * 6 + kk) * 64 + lane) * 8);
        acc[nt] = __builtin_amdgcn_mfma_f32_16x16x32_bf16(af, bf, acc[nt], 0, 0, 0);
      }
    }
  }
#pragma unroll
  for (int nt = 0; nt < 4; ++nt)
#pragma unroll
    for (int r = 0; r < 4; ++r)
      sH[(mt * 16 + hl * 4 + r) * SHB + nt * 16 + ll] = f2bf(fmaxf(acc[nt][r], 0.f));
  __syncthreads();
  f32x4 acc2[4];
#pragma unroll
  for (int nt = 0; nt < 4; ++nt) {
    float b = b2[nt * 16 + ll];
    acc2[nt].x = b; acc2[nt].y = b; acc2[nt].z = b; acc2[nt].w = b;
  }
  {
    const unsigned short* hBase = sH + (mt * 16 + ll) * SHB + hl * 8;
#pragma unroll
    for (int kk = 0; kk < 2; ++kk) {
      bf16x8 af = *(const bf16x8*)(hBase + kk * 32);
#pragma unroll
      for (int nt = 0; nt < 4; ++nt) {
        bf16x8 bf = *(const bf16x8*)(wB2 + ((size_t)(nt * 2 + kk) * 64 + lane) * 8);
        acc2[nt] = __builtin_amdgcn_mfma_f32_16x16x32_bf16(af, bf, acc2[nt], 0, 0, 0);
      }
    }
  }
#pragma unroll
  for (int r = 0; r < 4; ++r) {
    int t = mt * 16 + hl * 4 + r;
    int eid = e0 + t;
    int sN = src[eid], dN = dst[eid];
    const float* xr = x + (size_t)sN * D;
    const float* er = &sE[t * SEB];
    float* ar = agg + (size_t)dN * D;
#pragma unroll
    for (int nt = 0; nt < 4; ++nt) {
      int j = nt * 16 + ll;
      atomicAdd(ar + j, fmaxf(xr[j] + fmaf(0.5f, acc2[nt][r], er[j]), 0.f));
    }
  }
}

// ---------------- head (fallback tier only) ----------------
__global__ __launch_bounds__(256) void head_kernel(
    const float* __restrict__ x, const float* __restrict__ w,
    const float* __restrict__ b, float* __restrict__ out) {
  int nid = blockIdx.x * blockDim.x + threadIdx.x;
  if (nid >= NN) return;
  const float* xr = x + (size_t)nid * D;
  float a0 = b[0], a1 = b[1];
  for (int k = 0; k < D; ++k) {
    float v = xr[k];
    a0 = fmaf(v, w[k * 2 + 0], a0);
    a1 = fmaf(v, w[k * 2 + 1], a1);
  }
  out[nid * 2 + 0] = a0;
  out[nid * 2 + 1] = a1;
}

extern "C" void kernel_launch(void* const* d_in, const int* in_sizes, int n_in,
                              void* d_out, int out_size, void* d_ws, size_t ws_size,
                              hipStream_t stream) {
  const float* x0  = (const float*)d_in[0];
  const float* e0  = (const float*)d_in[1];
  const int*   ei  = (const int*)d_in[2];
  const float* gw1 = (const float*)d_in[3];
  const float* gb1 = (const float*)d_in[4];
  const float* gw2 = (const float*)d_in[5];
  const float* gb2 = (const float*)d_in[6];
  const float* ew1 = (const float*)d_in[7];
  const float* eb1 = (const float*)d_in[8];
  const float* ew2 = (const float*)d_in[9];
  const float* eb2 = (const float*)d_in[10];
  const float* lng = (const float*)d_in[11];
  const float* lnb = (const float*)d_in[12];
  const float* hw  = (const float*)d_in[13];
  const float* hb  = (const float*)d_in[14];
  float* out = (float*)d_out;

  char* ws = (char*)d_ws;
  const size_t SZ_X     = (size_t)NN * D * 4;             // 12.8 MB
  const size_t OFF_WB1  = 0;
  const size_t OFF_WB2  = OFF_WB1 + 24576;
  const size_t OFF_DEG  = OFF_WB2 + 8192;
  const size_t OFF_OFFS = OFF_DEG + 200704;
  const size_t OFF_CUR  = OFF_OFFS + 200704;
  const size_t OFF_BSUM = OFF_CUR + 200704;
  const size_t OFF_EPAIR= OFF_BSUM + 512;                 // 6.4 MB
  const size_t OFF_DCSR = OFF_EPAIR + (size_t)NE * 8;     // 3.2 MB
  const size_t OFF_POS  = OFF_DCSR + (size_t)NE * 4;      // 3.2 MB
  const size_t OFF_X1B  = OFF_POS + (size_t)NE * 4;       // 6.4 MB
  const size_t OFF_AGG  = OFF_X1B + (size_t)NN * D * 2;   // 12.8 MB
  const size_t OFF_ECSR = OFF_AGG + SZ_X;                 // 102.4 MB
  const size_t NEED_A   = OFF_ECSR + (size_t)NE * D * 2;  // ~135 MB

  unsigned short* wB1 = (unsigned short*)(ws + OFF_WB1);
  unsigned short* wB2 = (unsigned short*)(ws + OFF_WB2);
  int* deg  = (int*)(ws + OFF_DEG);
  int* offs = (int*)(ws + OFF_OFFS);
  int* cur  = (int*)(ws + OFF_CUR);
  int* bsum = (int*)(ws + OFF_BSUM);
  int2* epair = (int2*)(ws + OFF_EPAIR);
  int* dcsr = (int*)(ws + OFF_DCSR);
  int* pos  = (int*)(ws + OFF_POS);
  unsigned short* x1b  = (unsigned short*)(ws + OFF_X1B);
  float* agg = (float*)(ws + OFF_AGG);
  unsigned short* ecsr = (unsigned short*)(ws + OFF_ECSR);

  const int* src = ei;
  const int* dst = ei + NE;

  const int nodeBlocks = (NN + 63) / 64;     // 782
  const int edgeBlocks = NE / 64;            // 12500
  const int scanBlocks = (NN + 1023) / 1024; // 49

  pack_weights_kernel<<<8, 256, 0, stream>>>(ew1, ew2, wB1, wB2);

  if (ws_size >= NEED_A) {
    // ---- CSR build (by dst) ----
    zero_int_kernel<<<(NN + 255) / 256, 256, 0, stream>>>(deg, NN);
    count_kernel<<<(NE + 255) / 256, 256, 0, stream>>>(dst, deg);
    scan_reduce_kernel<<<scanBlocks, 1024, 0, stream>>>(deg, bsum);
    scan_final_kernel<<<scanBlocks, 1024, 0, stream>>>(deg, bsum, offs, cur);
    fill_kernel<<<(NE + 255) / 256, 256, 0, stream>>>(src, dst, cur, epair, dcsr, pos);

    // ---- permute e0 into CSR order ----
    permute_e_kernel<<<(NE * 4 + 255) / 256, 256, 0, stream>>>(e0, pos, ecsr);

    // ---- zero layer-1 agg ----
    zero_f4_kernel<<<(NN * D / 4 + 255) / 256, 256, 0, stream>>>(
        (float4*)agg, NN * D / 4);

    // ---- layer 0: fused gather + node MLP -> x1b ----
    node_mlp_g0_kernel<<<nodeBlocks, 512, 0, stream>>>(
        x0, ecsr, epair, offs, gw1, gb1, gw2, gb2, lng, lnb, x1b);

    // ---- layer-0 edge update (MFMA) + parallel segment reduce -> agg ----
    edge_mfma_seg_kernel<<<edgeBlocks, 256, 0, stream>>>(
        x1b, ecsr, epair, dcsr, wB1, eb1, wB2, eb2, agg);

    // ---- layer 1: plain node MLP (x1b + agg) + fused head ----
    node_mlp1_kernel<<<nodeBlocks, 512, 0, stream>>>(
        x1b, agg, gw1 + D * D, gb1 + D, gw2 + D * D, gb2 + D,
        lng + D, lnb + D, hw, hb, out);
  } else {
    // ---- fallback: atomic path (no CSR) ----
    float* x1f  = (float*)(ws + OFF_EPAIR);
    float* fagg = (float*)(ws + OFF_EPAIR + SZ_X);
    float* x2   = (float*)(ws + OFF_EPAIR + 2 * SZ_X);
    zero_f4_kernel<<<(NN * D / 4 + 255) / 256, 256, 0, stream>>>(
        (float4*)fagg, NN * D / 4);
    scatter_kernel<<<(NE * 16 + 255) / 256, 256, 0, stream>>>(x0, e0, src, dst, fagg);
    node_mlp_kernel<<<nodeBlocks, 256, 0, stream>>>(
        x0, fagg, gw1, gb1, gw2, gb2, lng, lnb, x1f);
    zero_f4_kernel<<<(NN * D / 4 + 255) / 256, 256, 0, stream>>>(
        (float4*)fagg, NN * D / 4);
    edge_mfma_atomic_kernel<<<edgeBlocks, 256, 0, stream>>>(
        x1f, e0, src, dst, wB1, eb1, wB2, eb2, fagg);
    node_mlp_kernel<<<nodeBlocks, 256, 0, stream>>>(
        x1f, fagg, gw1 + D * D, gb1 + D, gw2 + D * D, gb2 + D, lng + D, lnb + D, x2);
    head_kernel<<<(NN + 255) / 256, 256, 0, stream>>>(x2, hw, hb, out);
  }
}

// Round 16
// 330.204 us; speedup vs baseline: 1.2636x; 1.1140x over previous
//
#include <hip/hip_runtime.h>
#include <hip/hip_bf16.h>

#define NN 50000
#define NE 800000
#define D 64
#define K3 (3 * D)
#define LNEPS 1e-5f
#define STR 68    // f32 LDS row stride (node kernels)
#define SINB 200  // bf16 LDS row stride, edge input tile
#define SHB 72    // bf16 LDS row stride (fallback edge kernel)
#define MSTR 68   // f32 LDS row stride, msgF reduce tile
#define SEB 68    // f32 LDS row stride (fallback edge kernel)

typedef __attribute__((ext_vector_type(8))) short bf16x8;
typedef __attribute__((ext_vector_type(4))) float f32x4;

// hardware bf16 conversions (RNE)
__device__ __forceinline__ unsigned cvt2(float lo, float hi) {
  __hip_bfloat162 h = __float22bfloat162_rn(make_float2(lo, hi));
  return *(unsigned*)&h;
}
__device__ __forceinline__ unsigned short f2bf(float f) {
  __hip_bfloat16 h = __float2bfloat16(f);
  return *(unsigned short*)&h;
}
__device__ __forceinline__ float bf2f(unsigned short s) {
  return __uint_as_float((unsigned)s << 16);
}

#define FMA4x4(v, w)                                                  \
  a0.x = fmaf(v.x, w.x, a0.x); a0.y = fmaf(v.x, w.y, a0.y);           \
  a0.z = fmaf(v.x, w.z, a0.z); a0.w = fmaf(v.x, w.w, a0.w);           \
  a1.x = fmaf(v.y, w.x, a1.x); a1.y = fmaf(v.y, w.y, a1.y);           \
  a1.z = fmaf(v.y, w.z, a1.z); a1.w = fmaf(v.y, w.w, a1.w);           \
  a2.x = fmaf(v.z, w.x, a2.x); a2.y = fmaf(v.z, w.y, a2.y);           \
  a2.z = fmaf(v.z, w.z, a2.z); a2.w = fmaf(v.z, w.w, a2.w);           \
  a3.x = fmaf(v.w, w.x, a3.x); a3.y = fmaf(v.w, w.y, a3.y);           \
  a3.z = fmaf(v.w, w.z, a3.z); a3.w = fmaf(v.w, w.w, a3.w);

#define FMA2x4(v, w)                                                  \
  a0.x = fmaf(v.x, w.x, a0.x); a0.y = fmaf(v.x, w.y, a0.y);           \
  a0.z = fmaf(v.x, w.z, a0.z); a0.w = fmaf(v.x, w.w, a0.w);           \
  a1.x = fmaf(v.y, w.x, a1.x); a1.y = fmaf(v.y, w.y, a1.y);           \
  a1.z = fmaf(v.y, w.z, a1.z); a1.w = fmaf(v.y, w.w, a1.w);

#define HSTORE_RELU(buf)                                              \
  buf[(j0+0)*STR + t0+0] = fmaxf(a0.x, 0.f);                          \
  buf[(j0+1)*STR + t0+0] = fmaxf(a0.y, 0.f);                          \
  buf[(j0+2)*STR + t0+0] = fmaxf(a0.z, 0.f);                          \
  buf[(j0+3)*STR + t0+0] = fmaxf(a0.w, 0.f);                          \
  buf[(j0+0)*STR + t0+1] = fmaxf(a1.x, 0.f);                          \
  buf[(j0+1)*STR + t0+1] = fmaxf(a1.y, 0.f);                          \
  buf[(j0+2)*STR + t0+1] = fmaxf(a1.z, 0.f);                          \
  buf[(j0+3)*STR + t0+1] = fmaxf(a1.w, 0.f);                          \
  buf[(j0+0)*STR + t0+2] = fmaxf(a2.x, 0.f);                          \
  buf[(j0+1)*STR + t0+2] = fmaxf(a2.y, 0.f);                          \
  buf[(j0+2)*STR + t0+2] = fmaxf(a2.z, 0.f);                          \
  buf[(j0+3)*STR + t0+2] = fmaxf(a2.w, 0.f);                          \
  buf[(j0+0)*STR + t0+3] = fmaxf(a3.x, 0.f);                          \
  buf[(j0+1)*STR + t0+3] = fmaxf(a3.y, 0.f);                          \
  buf[(j0+2)*STR + t0+3] = fmaxf(a3.z, 0.f);                          \
  buf[(j0+3)*STR + t0+3] = fmaxf(a3.w, 0.f);

// ---------------- zero kernels ----------------
__global__ __launch_bounds__(256) void zero_int_kernel(int* __restrict__ p, int n) {
  int i = blockIdx.x * 256 + threadIdx.x;
  if (i < n) p[i] = 0;
}
__global__ __launch_bounds__(256) void zero_f4_kernel(float4* __restrict__ p, int n) {
  int i = blockIdx.x * 256 + threadIdx.x;
  if (i < n) p[i] = make_float4(0.f, 0.f, 0.f, 0.f);
}

// ---------------- CSR build ----------------
__global__ __launch_bounds__(256) void count_kernel(
    const int* __restrict__ dst, int* __restrict__ deg) {
  int e = blockIdx.x * 256 + threadIdx.x;
  if (e < NE) atomicAdd(&deg[dst[e]], 1);
}

__global__ __launch_bounds__(1024) void scan_reduce_kernel(
    const int* __restrict__ deg, int* __restrict__ bsum) {
  __shared__ int sS[16];
  int i = blockIdx.x * 1024 + threadIdx.x;
  int v = (i < NN) ? deg[i] : 0;
#pragma unroll
  for (int o = 32; o > 0; o >>= 1) v += __shfl_down(v, o, 64);
  if ((threadIdx.x & 63) == 0) sS[threadIdx.x >> 6] = v;
  __syncthreads();
  if (threadIdx.x == 0) {
    int s = 0;
#pragma unroll
    for (int k = 0; k < 16; ++k) s += sS[k];
    bsum[blockIdx.x] = s;
  }
}

__global__ __launch_bounds__(1024) void scan_final_kernel(
    const int* __restrict__ deg, const int* __restrict__ bsum,
    int* __restrict__ off, int* __restrict__ cur) {
  __shared__ int sD[1024];
  __shared__ int sOfs;
  const int t = threadIdx.x;
  const int b = blockIdx.x;
  int i = b * 1024 + t;
  int v = (i < NN) ? deg[i] : 0;
  sD[t] = v;
  if (t == 0) {
    int o = 0;
    for (int k = 0; k < b; ++k) o += bsum[k];
    sOfs = o;
  }
  __syncthreads();
  for (int st = 1; st < 1024; st <<= 1) {
    int add = (t >= st) ? sD[t - st] : 0;
    __syncthreads();
    sD[t] += add;
    __syncthreads();
  }
  if (i < NN) {
    int excl = sOfs + sD[t] - v;
    off[i] = excl;
    cur[i] = excl;
    if (i == NN - 1) off[NN] = NE;
  }
}

// ---------------- merged fill + permute ----------------
// 4 lanes per edge; lane q=0 claims CSR slot p via atomic, broadcast via shfl;
// all lanes move 32B of e (coalesced read -> scattered bf16 write to ecsr[p]);
// lane q=0 writes sdcsr[p] = {src, dst}.
__global__ __launch_bounds__(256) void fillperm_kernel(
    const float* __restrict__ e, const int* __restrict__ src,
    const int* __restrict__ dst, int* __restrict__ cur,
    int2* __restrict__ sdcsr, unsigned short* __restrict__ ecsr) {
  int tid = blockIdx.x * 256 + threadIdx.x;  // NE*4 threads
  int eid = tid >> 2, q = tid & 3;
  if (eid >= NE) return;
  int lane = threadIdx.x & 63;
  int s = src[eid], d = dst[eid];
  int p = 0;
  if (q == 0) p = atomicAdd(&cur[d], 1);
  p = __shfl(p, lane & ~3, 64);
  const float4* ep = (const float4*)(e + (size_t)eid * D + q * 16);
  float4 v0 = ep[0], v1 = ep[1], v2 = ep[2], v3 = ep[3];
  uint4 u0, u1;
  u0.x = cvt2(v0.x, v0.y); u0.y = cvt2(v0.z, v0.w);
  u0.z = cvt2(v1.x, v1.y); u0.w = cvt2(v1.z, v1.w);
  u1.x = cvt2(v2.x, v2.y); u1.y = cvt2(v2.z, v2.w);
  u1.z = cvt2(v3.x, v3.y); u1.w = cvt2(v3.z, v3.w);
  uint4* dp = (uint4*)(ecsr + (size_t)p * D + q * 16);
  dp[0] = u0;
  dp[1] = u1;
  if (q == 0) sdcsr[p] = make_int2(s, d);
}

// ---------------- pack edge-MLP weights ----------------
__global__ __launch_bounds__(256) void pack_weights_kernel(
    const float* __restrict__ w1, const float* __restrict__ w2,
    unsigned short* __restrict__ wB1, unsigned short* __restrict__ wB2) {
  int tid = blockIdx.x * 256 + threadIdx.x;
  const float* wsrc;
  unsigned short* wdst;
  int kb, j, slot;
  if (tid < 1536) {
    int nt = tid / 384, kk = (tid / 64) % 6, l = tid & 63;
    kb = kk * 32 + (l >> 4) * 8;
    j = nt * 16 + (l & 15);
    wsrc = w1; wdst = wB1; slot = tid;
  } else {
    int t = tid - 1536;
    int nt = t / 128, kk = (t / 64) & 1, l = t & 63;
    kb = kk * 32 + (l >> 4) * 8;
    j = nt * 16 + (l & 15);
    wsrc = w2; wdst = wB2; slot = t;
  }
  unsigned short b[8];
#pragma unroll
  for (int i = 0; i < 8; ++i) b[i] = f2bf(wsrc[(kb + i) * D + j]);
  uint4 v;
  v.x = (unsigned)b[0] | ((unsigned)b[1] << 16);
  v.y = (unsigned)b[2] | ((unsigned)b[3] << 16);
  v.z = (unsigned)b[4] | ((unsigned)b[5] << 16);
  v.w = (unsigned)b[6] | ((unsigned)b[7] << 16);
  *(uint4*)(wdst + (size_t)slot * 8) = v;
}

// ---------------- 512-thread MLP tail ----------------
__device__ __forceinline__ void mlp_tail512(
    float* sIN, float* sH, float* sPS, float* sPQ, float* sMu, float* sRs,
    const float* __restrict__ w1, const float* __restrict__ b1,
    const float* __restrict__ w2, const float* __restrict__ b2,
    const float* __restrict__ g, const float* __restrict__ bln,
    float* __restrict__ xo, unsigned short* __restrict__ xob,
    const float* __restrict__ hw, const float* __restrict__ hb,
    float* __restrict__ outh,
    int n0, int tid) {
  __syncthreads();
  const int tj = tid & 15, tt = tid >> 4;   // 16 x 32
  const int j0 = tj * 4, t0 = tt * 2;
  float4 a0, a1;

  {
    float4 bv = *(const float4*)(b1 + j0);
    a0 = a1 = bv;
    for (int k = 0; k < D; ++k) {
      float4 w = *(const float4*)(w1 + k * D + j0);
      float2 v = *(const float2*)&sIN[k * STR + t0];
      FMA2x4(v, w)
    }
  }
  sH[(j0 + 0) * STR + t0 + 0] = fmaxf(a0.x, 0.f);
  sH[(j0 + 1) * STR + t0 + 0] = fmaxf(a0.y, 0.f);
  sH[(j0 + 2) * STR + t0 + 0] = fmaxf(a0.z, 0.f);
  sH[(j0 + 3) * STR + t0 + 0] = fmaxf(a0.w, 0.f);
  sH[(j0 + 0) * STR + t0 + 1] = fmaxf(a1.x, 0.f);
  sH[(j0 + 1) * STR + t0 + 1] = fmaxf(a1.y, 0.f);
  sH[(j0 + 2) * STR + t0 + 1] = fmaxf(a1.z, 0.f);
  sH[(j0 + 3) * STR + t0 + 1] = fmaxf(a1.w, 0.f);
  __syncthreads();

  {
    float4 bv = *(const float4*)(b2 + j0);
    a0 = a1 = bv;
    for (int k = 0; k < D; ++k) {
      float4 w = *(const float4*)(w2 + k * D + j0);
      float2 v = *(const float2*)&sH[k * STR + t0];
      FMA2x4(v, w)
    }
  }
  __syncthreads();
  *(float4*)&sH[(t0 + 0) * STR + j0] = a0;
  *(float4*)&sH[(t0 + 1) * STR + j0] = a1;
  __syncthreads();

  {
    const int t = tid & 63, p = tid >> 6;
    const float* r = &sH[t * STR + p * 8];
    float s = 0.f, q = 0.f;
#pragma unroll
    for (int i = 0; i < 8; ++i) { float v = r[i]; s += v; q = fmaf(v, v, q); }
    sPS[p * 64 + t] = s;
    sPQ[p * 64 + t] = q;
  }
  __syncthreads();
  if (tid < 64) {
    float s = 0.f, q = 0.f;
#pragma unroll
    for (int p = 0; p < 8; ++p) { s += sPS[p * 64 + tid]; q += sPQ[p * 64 + tid]; }
    float mu = s * (1.f / 64.f);
    float var = q * (1.f / 64.f) - mu * mu;
    sMu[tid] = mu;
    sRs[tid] = rsqrtf(var + LNEPS);
  }
  __syncthreads();

  {
    const int t = tid >> 3, c = (tid & 7) * 8;
    int node = n0 + t;
    if (node < NN) {
      float mu = sMu[t], rs = sRs[t];
      float4 v0 = *(const float4*)&sH[t * STR + c + 0];
      float4 v1 = *(const float4*)&sH[t * STR + c + 4];
      float4 g0v = *(const float4*)(g + c + 0);
      float4 g1v = *(const float4*)(g + c + 4);
      float4 b0v = *(const float4*)(bln + c + 0);
      float4 b1v = *(const float4*)(bln + c + 4);
      float4 r0, r1;
      r0.x = fmaxf(fmaf((v0.x - mu) * rs, g0v.x, b0v.x), 0.f);
      r0.y = fmaxf(fmaf((v0.y - mu) * rs, g0v.y, b0v.y), 0.f);
      r0.z = fmaxf(fmaf((v0.z - mu) * rs, g0v.z, b0v.z), 0.f);
      r0.w = fmaxf(fmaf((v0.w - mu) * rs, g0v.w, b0v.w), 0.f);
      r1.x = fmaxf(fmaf((v1.x - mu) * rs, g1v.x, b1v.x), 0.f);
      r1.y = fmaxf(fmaf((v1.y - mu) * rs, g1v.y, b1v.y), 0.f);
      r1.z = fmaxf(fmaf((v1.z - mu) * rs, g1v.z, b1v.z), 0.f);
      r1.w = fmaxf(fmaf((v1.w - mu) * rs, g1v.w, b1v.w), 0.f);
      if (outh) {
        float h0, h1;
        h0 = r0.x * hw[(c + 0) * 2 + 0] + r0.y * hw[(c + 1) * 2 + 0] +
             r0.z * hw[(c + 2) * 2 + 0] + r0.w * hw[(c + 3) * 2 + 0] +
             r1.x * hw[(c + 4) * 2 + 0] + r1.y * hw[(c + 5) * 2 + 0] +
             r1.z * hw[(c + 6) * 2 + 0] + r1.w * hw[(c + 7) * 2 + 0];
        h1 = r0.x * hw[(c + 0) * 2 + 1] + r0.y * hw[(c + 1) * 2 + 1] +
             r0.z * hw[(c + 2) * 2 + 1] + r0.w * hw[(c + 3) * 2 + 1] +
             r1.x * hw[(c + 4) * 2 + 1] + r1.y * hw[(c + 5) * 2 + 1] +
             r1.z * hw[(c + 6) * 2 + 1] + r1.w * hw[(c + 7) * 2 + 1];
#pragma unroll
        for (int o = 1; o < 8; o <<= 1) {
          h0 += __shfl_xor(h0, o, 64);
          h1 += __shfl_xor(h1, o, 64);
        }
        if ((tid & 7) == 0) {
          outh[node * 2 + 0] = h0 + hb[0];
          outh[node * 2 + 1] = h1 + hb[1];
        }
      } else {
        if (xo) {
          float* o = xo + (size_t)node * D + c;
          ((float4*)o)[0] = r0;
          ((float4*)o)[1] = r1;
        }
        if (xob) {
          uint4 u;
          u.x = cvt2(r0.x, r0.y); u.y = cvt2(r0.z, r0.w);
          u.z = cvt2(r1.x, r1.y); u.w = cvt2(r1.z, r1.w);
          *(uint4*)(xob + (size_t)node * D + c) = u;
        }
      }
    }
  }
}

// ---------------- layer-0: fused CSR gather (ecsr stream + cached x) + node MLP -> x1b ----------------
__global__ __launch_bounds__(512) void node_mlp_g0_kernel(
    const float* __restrict__ x, const unsigned short* __restrict__ ecsr,
    const int2* __restrict__ sdcsr, const int* __restrict__ off,
    const float* __restrict__ w1, const float* __restrict__ b1,
    const float* __restrict__ w2, const float* __restrict__ b2,
    const float* __restrict__ g, const float* __restrict__ bln,
    unsigned short* __restrict__ xob) {
  __shared__ float sIN[D * STR];
  __shared__ float sH[D * STR];
  __shared__ float sPS[512], sPQ[512], sMu[64], sRs[64];
  const int tid = threadIdx.x;
  const int n0 = blockIdx.x * 64;
  const int wv = tid >> 6, lane = tid & 63;
  for (int q = 0; q < 8; ++q) {
    int t = wv * 8 + q;
    int node = n0 + t;
    float acc = 0.f;
    if (node < NN) {
      acc = x[(size_t)node * D + lane];  // self term
      int beg = off[node], end = off[node + 1];
      const unsigned short* er = ecsr + (size_t)beg * D + lane;
      int cnt = end - beg, i = 0;
      for (; i + 3 < cnt; i += 4) {
        int s0 = sdcsr[beg + i + 0].x, s1 = sdcsr[beg + i + 1].x;
        int s2 = sdcsr[beg + i + 2].x, s3 = sdcsr[beg + i + 3].x;
        float xa = x[(size_t)s0 * D + lane], ea = bf2f(er[(size_t)(i + 0) * D]);
        float xb = x[(size_t)s1 * D + lane], eb = bf2f(er[(size_t)(i + 1) * D]);
        float xc = x[(size_t)s2 * D + lane], ec = bf2f(er[(size_t)(i + 2) * D]);
        float xd = x[(size_t)s3 * D + lane], ed = bf2f(er[(size_t)(i + 3) * D]);
        acc += (fmaxf(xa + ea, 0.f) + fmaxf(xb + eb, 0.f)) +
               (fmaxf(xc + ec, 0.f) + fmaxf(xd + ed, 0.f));
      }
      for (; i < cnt; ++i) {
        int s0 = sdcsr[beg + i].x;
        acc += fmaxf(x[(size_t)s0 * D + lane] + bf2f(er[(size_t)i * D]), 0.f);
      }
    }
    sIN[lane * STR + t] = acc;
  }
  mlp_tail512(sIN, sH, sPS, sPQ, sMu, sRs, w1, b1, w2, b2, g, bln,
              nullptr, xob, nullptr, nullptr, nullptr, n0, tid);
}

// ---------------- layer-1: plain node MLP (x1b + agg) + fused head ----------------
__global__ __launch_bounds__(512) void node_mlp1_kernel(
    const unsigned short* __restrict__ xb, const float* __restrict__ agg,
    const float* __restrict__ w1, const float* __restrict__ b1,
    const float* __restrict__ w2, const float* __restrict__ b2,
    const float* __restrict__ g, const float* __restrict__ bln,
    const float* __restrict__ hw, const float* __restrict__ hb,
    float* __restrict__ outh) {
  __shared__ float sIN[D * STR];
  __shared__ float sH[D * STR];
  __shared__ float sPS[512], sPQ[512], sMu[64], sRs[64];
  const int tid = threadIdx.x;
  const int n0 = blockIdx.x * 64;
  {
    const int t = tid & 63, p = tid >> 6;  // 8 feats each
    int node = n0 + t;
    int cn = node < NN ? node : 0;
    const unsigned short* xr = xb + (size_t)cn * D + p * 8;
    const float* ar = agg + (size_t)cn * D + p * 8;
    uint4 xv = *(const uint4*)xr;
    float4 a0v = ((const float4*)ar)[0];
    float4 a1v = ((const float4*)ar)[1];
    int k = p * 8;
    sIN[(k + 0) * STR + t] = bf2f((unsigned short)(xv.x & 0xFFFF)) + a0v.x;
    sIN[(k + 1) * STR + t] = bf2f((unsigned short)(xv.x >> 16)) + a0v.y;
    sIN[(k + 2) * STR + t] = bf2f((unsigned short)(xv.y & 0xFFFF)) + a0v.z;
    sIN[(k + 3) * STR + t] = bf2f((unsigned short)(xv.y >> 16)) + a0v.w;
    sIN[(k + 4) * STR + t] = bf2f((unsigned short)(xv.z & 0xFFFF)) + a1v.x;
    sIN[(k + 5) * STR + t] = bf2f((unsigned short)(xv.z >> 16)) + a1v.y;
    sIN[(k + 6) * STR + t] = bf2f((unsigned short)(xv.w & 0xFFFF)) + a1v.z;
    sIN[(k + 7) * STR + t] = bf2f((unsigned short)(xv.w >> 16)) + a1v.w;
  }
  mlp_tail512(sIN, sH, sPS, sPQ, sMu, sRs, w1, b1, w2, b2, g, bln,
              nullptr, nullptr, hw, hb, outh, n0, tid);
}

// ---------------- MFMA edge MLP + parallel in-LDS segment reduce -> agg atomics ----------------
// LDS: single sIN buffer; GEMM2's A-operand aliases the dead x[dst] columns (64..127).
__global__ __launch_bounds__(256) void edge_mfma_seg_kernel(
    const unsigned short* __restrict__ x1b, const unsigned short* __restrict__ ecsr,
    const int2* __restrict__ sdcsr,
    const unsigned short* __restrict__ wB1, const float* __restrict__ b1,
    const unsigned short* __restrict__ wB2, const float* __restrict__ b2,
    float* __restrict__ agg) {
  __shared__ unsigned short sIN[64 * SINB];  // 25600 B; cols 64..127 reused for relu(h);
                                             // whole buffer reused as f32 msgF[64][MSTR]
  __shared__ int sDst[64];

  const int tid = threadIdx.x;
  const int e0 = blockIdx.x * 64;  // CSR slot base
  const int lane = tid & 63;
  const int mt = tid >> 6;
  const int hl = lane >> 4;
  const int ll = lane & 15;

  // ---- stage: pure 16B copies
  {
    const int t = tid & 63, p = tid >> 6;
    int slot = e0 + t;
    int2 sd = sdcsr[slot];
    int sN = sd.x, dN = sd.y;
    if (p == 0) sDst[t] = dN;
    const uint4* xs = (const uint4*)(x1b + (size_t)sN * D + p * 16);
    const uint4* xd = (const uint4*)(x1b + (size_t)dN * D + p * 16);
    const uint4* ec = (const uint4*)(ecsr + (size_t)slot * D + p * 16);
    uint4* r0 = (uint4*)(sIN + t * SINB + p * 16);
    uint4* r1 = (uint4*)(sIN + t * SINB + 64 + p * 16);
    uint4* r2 = (uint4*)(sIN + t * SINB + 128 + p * 16);
    uint4 a0v = xs[0], a1v = xs[1];
    uint4 b0v = xd[0], b1v = xd[1];
    uint4 c0v = ec[0], c1v = ec[1];
    r0[0] = a0v; r0[1] = a1v;
    r1[0] = b0v; r1[1] = b1v;
    r2[0] = c0v; r2[1] = c1v;
  }
  __syncthreads();

  // ---- GEMM1 (K=192): reads sIN cols 0..191
  f32x4 acc[4];
#pragma unroll
  for (int nt = 0; nt < 4; ++nt) {
    float b = b1[nt * 16 + ll];
    acc[nt].x = b; acc[nt].y = b; acc[nt].z = b; acc[nt].w = b;
  }
  {
    const unsigned short* aBase = sIN + (mt * 16 + ll) * SINB + hl * 8;
#pragma unroll
    for (int kk = 0; kk < 6; ++kk) {
      bf16x8 af = *(const bf16x8*)(aBase + kk * 32);
#pragma unroll
      for (int nt = 0; nt < 4; ++nt) {
        bf16x8 bf = *(const bf16x8*)(wB1 + ((size_t)(nt * 6 + kk) * 64 + lane) * 8);
        acc[nt] = __builtin_amdgcn_mfma_f32_16x16x32_bf16(af, bf, acc[nt], 0, 0, 0);
      }
    }
  }
  __syncthreads();  // all GEMM1 reads done; cols 64..127 now dead -> reuse for relu(h)

#pragma unroll
  for (int nt = 0; nt < 4; ++nt)
#pragma unroll
    for (int r = 0; r < 4; ++r)
      sIN[(mt * 16 + hl * 4 + r) * SINB + 64 + nt * 16 + ll] =
          f2bf(fmaxf(acc[nt][r], 0.f));
  __syncthreads();

  // ---- GEMM2 (K=64): A from aliased cols 64..127
  f32x4 acc2[4];
#pragma unroll
  for (int nt = 0; nt < 4; ++nt) {
    float b = b2[nt * 16 + ll];
    acc2[nt].x = b; acc2[nt].y = b; acc2[nt].z = b; acc2[nt].w = b;
  }
  {
    const unsigned short* hBase = sIN + (mt * 16 + ll) * SINB + 64 + hl * 8;
#pragma unroll
    for (int kk = 0; kk < 2; ++kk) {
      bf16x8 af = *(const bf16x8*)(hBase + kk * 32);
#pragma unroll
      for (int nt = 0; nt < 4; ++nt) {
        bf16x8 bf = *(const bf16x8*)(wB2 + ((size_t)(nt * 2 + kk) * 64 + lane) * 8);
        acc2[nt] = __builtin_amdgcn_mfma_f32_16x16x32_bf16(af, bf, acc2[nt], 0, 0, 0);
      }
    }
  }

  // ---- msg in registers: relu(x[src] + e + 0.5*o)  (cols 0..63 and 128..191 intact)
  float m0x, m0y, m0z, m0w, m1x, m1y, m1z, m1w;
  float m2x, m2y, m2z, m2w, m3x, m3y, m3z, m3w;
  {
    const unsigned short* x0r = sIN + (mt * 16 + hl * 4 + 0) * SINB;
    const unsigned short* x1r = sIN + (mt * 16 + hl * 4 + 1) * SINB;
    const unsigned short* x2r = sIN + (mt * 16 + hl * 4 + 2) * SINB;
    const unsigned short* x3r = sIN + (mt * 16 + hl * 4 + 3) * SINB;
#define MSG(xr, nt, r) fmaxf(bf2f(xr[nt * 16 + ll]) + fmaf(0.5f, acc2[nt][r], bf2f(xr[128 + nt * 16 + ll])), 0.f)
    m0x = MSG(x0r, 0, 0); m0y = MSG(x0r, 1, 0); m0z = MSG(x0r, 2, 0); m0w = MSG(x0r, 3, 0);
    m1x = MSG(x1r, 0, 1); m1y = MSG(x1r, 1, 1); m1z = MSG(x1r, 2, 1); m1w = MSG(x1r, 3, 1);
    m2x = MSG(x2r, 0, 2); m2y = MSG(x2r, 1, 2); m2z = MSG(x2r, 2, 2); m2w = MSG(x2r, 3, 2);
    m3x = MSG(x3r, 0, 3); m3y = MSG(x3r, 1, 3); m3z = MSG(x3r, 2, 3); m3w = MSG(x3r, 3, 3);
#undef MSG
  }
  __syncthreads();  // all sIN reads done; reuse as f32 msgF

  float* msgF = (float*)sIN;  // [64][MSTR], 17408 B
  {
    int tb = mt * 16 + hl * 4;
    msgF[(tb + 0) * MSTR + 0 * 16 + ll] = m0x;
    msgF[(tb + 0) * MSTR + 1 * 16 + ll] = m0y;
    msgF[(tb + 0) * MSTR + 2 * 16 + ll] = m0z;
    msgF[(tb + 0) * MSTR + 3 * 16 + ll] = m0w;
    msgF[(tb + 1) * MSTR + 0 * 16 + ll] = m1x;
    msgF[(tb + 1) * MSTR + 1 * 16 + ll] = m1y;
    msgF[(tb + 1) * MSTR + 2 * 16 + ll] = m1z;
    msgF[(tb + 1) * MSTR + 3 * 16 + ll] = m1w;
    msgF[(tb + 2) * MSTR + 0 * 16 + ll] = m2x;
    msgF[(tb + 2) * MSTR + 1 * 16 + ll] = m2y;
    msgF[(tb + 2) * MSTR + 2 * 16 + ll] = m2z;
    msgF[(tb + 2) * MSTR + 3 * 16 + ll] = m2w;
    msgF[(tb + 3) * MSTR + 0 * 16 + ll] = m3x;
    msgF[(tb + 3) * MSTR + 1 * 16 + ll] = m3y;
    msgF[(tb + 3) * MSTR + 2 * 16 + ll] = m3z;
    msgF[(tb + 3) * MSTR + 3 * 16 + ll] = m3w;
  }
  __syncthreads();

  // ---- parallel segment reduce: thread (p, j) walks 16 rows of column j
  {
    const int p = tid >> 6, j = tid & 63;
    const int rbeg = p * 16, rend = rbeg + 16;
    int cur = sDst[rbeg];
    float sum = msgF[rbeg * MSTR + j];
    for (int t = rbeg + 1; t < rend; ++t) {
      int d = sDst[t];
      float v = msgF[t * MSTR + j];
      if (d != cur) {
        atomicAdd(&agg[(size_t)cur * D + j], sum);
        cur = d;
        sum = v;
      } else {
        sum += v;
      }
    }
    atomicAdd(&agg[(size_t)cur * D + j], sum);
  }
}

// ---------------- legacy kernels (fallback tier) ----------------
__global__ __launch_bounds__(256) void scatter_kernel(
    const float* __restrict__ x, const float* __restrict__ e,
    const int* __restrict__ src, const int* __restrict__ dst,
    float* __restrict__ agg) {
  int tid = blockIdx.x * blockDim.x + threadIdx.x;
  if (tid >= NE * 16) return;
  int eid = tid >> 4, q = tid & 15;
  int s = src[eid], d = dst[eid];
  float4 xv = ((const float4*)(x + (size_t)s * D))[q];
  float4 ev = ((const float4*)(e + (size_t)eid * D))[q];
  float* a = agg + (size_t)d * D + q * 4;
  atomicAdd(a + 0, fmaxf(xv.x + ev.x, 0.f));
  atomicAdd(a + 1, fmaxf(xv.y + ev.y, 0.f));
  atomicAdd(a + 2, fmaxf(xv.z + ev.z, 0.f));
  atomicAdd(a + 3, fmaxf(xv.w + ev.w, 0.f));
}

__device__ __forceinline__ void mlp_tail256(
    float* sIN, float* sH, float* sPS, float* sPQ, float* sMu, float* sRs,
    const float* __restrict__ w1, const float* __restrict__ b1,
    const float* __restrict__ w2, const float* __restrict__ b2,
    const float* __restrict__ g, const float* __restrict__ bln,
    float* __restrict__ xo, int n0, int tid) {
  __syncthreads();
  const int tj = tid & 15, tt = tid >> 4;
  const int j0 = tj * 4, t0 = tt * 4;
  float4 a0, a1, a2, a3;
  {
    float4 bv = *(const float4*)(b1 + j0);
    a0 = a1 = a2 = a3 = bv;
    for (int k = 0; k < D; ++k) {
      float4 w = *(const float4*)(w1 + k * D + j0);
      float4 v = *(const float4*)&sIN[k * STR + t0];
      FMA4x4(v, w)
    }
  }
  HSTORE_RELU(sH)
  __syncthreads();
  {
    float4 bv = *(const float4*)(b2 + j0);
    a0 = a1 = a2 = a3 = bv;
    for (int k = 0; k < D; ++k) {
      float4 w = *(const float4*)(w2 + k * D + j0);
      float4 v = *(const float4*)&sH[k * STR + t0];
      FMA4x4(v, w)
    }
  }
  __syncthreads();
  *(float4*)&sH[(t0 + 0) * STR + j0] = a0;
  *(float4*)&sH[(t0 + 1) * STR + j0] = a1;
  *(float4*)&sH[(t0 + 2) * STR + j0] = a2;
  *(float4*)&sH[(t0 + 3) * STR + j0] = a3;
  __syncthreads();
  {
    const int t = tid & 63, p = tid >> 6;
    const float* r = &sH[t * STR + p * 16];
    float s = 0.f, q = 0.f;
#pragma unroll
    for (int i = 0; i < 16; ++i) { float v = r[i]; s += v; q = fmaf(v, v, q); }
    sPS[p * 64 + t] = s;
    sPQ[p * 64 + t] = q;
  }
  __syncthreads();
  if (tid < 64) {
    float s = sPS[tid] + sPS[64 + tid] + sPS[128 + tid] + sPS[192 + tid];
    float q = sPQ[tid] + sPQ[64 + tid] + sPQ[128 + tid] + sPQ[192 + tid];
    float mu = s * (1.f / 64.f);
    float var = q * (1.f / 64.f) - mu * mu;
    sMu[tid] = mu;
    sRs[tid] = rsqrtf(var + LNEPS);
  }
  __syncthreads();
  {
    const int t = tid >> 2, c = (tid & 3) * 16;
    int node = n0 + t;
    if (node < NN) {
      float mu = sMu[t], rs = sRs[t];
      float* o = xo + (size_t)node * D + c;
#pragma unroll
      for (int i = 0; i < 4; ++i) {
        float4 v = *(const float4*)&sH[t * STR + c + i * 4];
        float4 gv = *(const float4*)(g + c + i * 4);
        float4 bv = *(const float4*)(bln + c + i * 4);
        float4 r;
        r.x = fmaxf(fmaf((v.x - mu) * rs, gv.x, bv.x), 0.f);
        r.y = fmaxf(fmaf((v.y - mu) * rs, gv.y, bv.y), 0.f);
        r.z = fmaxf(fmaf((v.z - mu) * rs, gv.z, bv.z), 0.f);
        r.w = fmaxf(fmaf((v.w - mu) * rs, gv.w, bv.w), 0.f);
        ((float4*)o)[i] = r;
      }
    }
  }
}

__global__ __launch_bounds__(256) void node_mlp_kernel(
    const float* __restrict__ x, const float* __restrict__ agg,
    const float* __restrict__ w1, const float* __restrict__ b1,
    const float* __restrict__ w2, const float* __restrict__ b2,
    const float* __restrict__ g, const float* __restrict__ bln,
    float* __restrict__ xo) {
  __shared__ float sIN[D * STR];
  __shared__ float sH[D * STR];
  __shared__ float sPS[256], sPQ[256], sMu[64], sRs[64];
  const int tid = threadIdx.x;
  const int n0 = blockIdx.x * 64;
  {
    const int t = tid & 63, p = tid >> 6;
    int node = n0 + t;
    int cn = node < NN ? node : 0;
    const float* xr = x + (size_t)cn * D + p * 16;
    const float* ar = agg + (size_t)cn * D + p * 16;
#pragma unroll
    for (int i = 0; i < 4; ++i) {
      float4 xv = ((const float4*)xr)[i];
      float4 av = ((const float4*)ar)[i];
      int k = p * 16 + i * 4;
      sIN[(k + 0) * STR + t] = xv.x + av.x;
      sIN[(k + 1) * STR + t] = xv.y + av.y;
      sIN[(k + 2) * STR + t] = xv.z + av.z;
      sIN[(k + 3) * STR + t] = xv.w + av.w;
    }
  }
  mlp_tail256(sIN, sH, sPS, sPQ, sMu, sRs, w1, b1, w2, b2, g, bln, xo, n0, tid);
}

__global__ __launch_bounds__(256) void edge_mfma_atomic_kernel(
    const float* __restrict__ x, const float* __restrict__ e,
    const int* __restrict__ src, const int* __restrict__ dst,
    const unsigned short* __restrict__ wB1, const float* __restrict__ b1,
    const unsigned short* __restrict__ wB2, const float* __restrict__ b2,
    float* __restrict__ agg) {
  __shared__ unsigned short sIN[64 * SINB];
  __shared__ unsigned short sH[64 * SHB];
  __shared__ float sE[64 * SEB];
  const int tid = threadIdx.x;
  const int e0 = blockIdx.x * 64;
  const int lane = tid & 63;
  const int mt = tid >> 6;
  const int hl = lane >> 4;
  const int ll = lane & 15;
  {
    const int t = tid & 63, p = tid >> 6;
    int eid = e0 + t;
    int sN = src[eid], dN = dst[eid];
    const float* g0 = x + (size_t)sN * D + p * 16;
    const float* g1 = x + (size_t)dN * D + p * 16;
    const float* g2 = e + (size_t)eid * D + p * 16;
    unsigned short* row = sIN + t * SINB + p * 16;
#pragma unroll
    for (int i = 0; i < 4; ++i) {
      float4 v0 = ((const float4*)g0)[i];
      float4 v1 = ((const float4*)g1)[i];
      float4 v2 = ((const float4*)g2)[i];
      uint2 u;
      u.x = cvt2(v0.x, v0.y); u.y = cvt2(v0.z, v0.w);
      *(uint2*)(row + i * 4) = u;
      u.x = cvt2(v1.x, v1.y); u.y = cvt2(v1.z, v1.w);
      *(uint2*)(row + 64 + i * 4) = u;
      u.x = cvt2(v2.x, v2.y); u.y = cvt2(v2.z, v2.w);
      *(uint2*)(row + 128 + i * 4) = u;
      *(float4*)&sE[t * SEB + p * 16 + i * 4] = v2;
    }
  }
  __syncthreads();
  f32x4 acc[4];
#pragma unroll
  for (int nt = 0; nt < 4; ++nt) {
    float b = b1[nt * 16 + ll];
    acc[nt].x = b; acc[nt].y = b; acc[nt].z = b; acc[nt].w = b;
  }
  {
    const unsigned short* aBase = sIN + (mt * 16 + ll) * SINB + hl * 8;
#pragma unroll
    for (int kk = 0; kk < 6; ++kk) {
      bf16x8 af = *(const bf16x8*)(aBase + kk * 32);
#pragma unroll
      for (int nt = 0; nt < 4; ++nt) {
        bf16x8 bf = *(const bf16x8*)(wB1 + ((size_t)(nt * 6 + kk) * 64 + lane) * 8);
        acc[nt] = __builtin_amdgcn_mfma_f32_16x16x32_bf16(af, bf, acc[nt], 0, 0, 0);
      }
    }
  }
#pragma unroll
  for (int nt = 0; nt < 4; ++nt)
#pragma unroll
    for (int r = 0; r < 4; ++r)
      sH[(mt * 16 + hl * 4 + r) * SHB + nt * 16 + ll] = f2bf(fmaxf(acc[nt][r], 0.f));
  __syncthreads();
  f32x4 acc2[4];
#pragma unroll
  for (int nt = 0; nt < 4; ++nt) {
    float b = b2[nt * 16 + ll];
    acc2[nt].x = b; acc2[nt].y = b; acc2[nt].z = b; acc2[nt].w = b;
  }
  {
    const unsigned short* hBase = sH + (mt * 16 + ll) * SHB + hl * 8;
#pragma unroll
    for (int kk = 0; kk < 2; ++kk) {
      bf16x8 af = *(const bf16x8*)(hBase + kk * 32);
#pragma unroll
      for (int nt = 0; nt < 4; ++nt) {
        bf16x8 bf = *(const bf16x8*)(wB2 + ((size_t)(nt * 2 + kk) * 64 + lane) * 8);
        acc2[nt] = __builtin_amdgcn_mfma_f32_16x16x32_bf16(af, bf, acc2[nt], 0, 0, 0);
      }
    }
  }
#pragma unroll
  for (int r = 0; r < 4; ++r) {
    int t = mt * 16 + hl * 4 + r;
    int eid = e0 + t;
    int sN = src[eid], dN = dst[eid];
    const float* xr = x + (size_t)sN * D;
    const float* er = &sE[t * SEB];
    float* ar = agg + (size_t)dN * D;
#pragma unroll
    for (int nt = 0; nt < 4; ++nt) {
      int j = nt * 16 + ll;
      atomicAdd(ar + j, fmaxf(xr[j] + fmaf(0.5f, acc2[nt][r], er[j]), 0.f));
    }
  }
}

// ---------------- head (fallback tier only) ----------------
__global__ __launch_bounds__(256) void head_kernel(
    const float* __restrict__ x, const float* __restrict__ w,
    const float* __restrict__ b, float* __restrict__ out) {
  int nid = blockIdx.x * blockDim.x + threadIdx.x;
  if (nid >= NN) return;
  const float* xr = x + (size_t)nid * D;
  float a0 = b[0], a1 = b[1];
  for (int k = 0; k < D; ++k) {
    float v = xr[k];
    a0 = fmaf(v, w[k * 2 + 0], a0);
    a1 = fmaf(v, w[k * 2 + 1], a1);
  }
  out[nid * 2 + 0] = a0;
  out[nid * 2 + 1] = a1;
}

extern "C" void kernel_launch(void* const* d_in, const int* in_sizes, int n_in,
                              void* d_out, int out_size, void* d_ws, size_t ws_size,
                              hipStream_t stream) {
  const float* x0  = (const float*)d_in[0];
  const float* e0  = (const float*)d_in[1];
  const int*   ei  = (const int*)d_in[2];
  const float* gw1 = (const float*)d_in[3];
  const float* gb1 = (const float*)d_in[4];
  const float* gw2 = (const float*)d_in[5];
  const float* gb2 = (const float*)d_in[6];
  const float* ew1 = (const float*)d_in[7];
  const float* eb1 = (const float*)d_in[8];
  const float* ew2 = (const float*)d_in[9];
  const float* eb2 = (const float*)d_in[10];
  const float* lng = (const float*)d_in[11];
  const float* lnb = (const float*)d_in[12];
  const float* hw  = (const float*)d_in[13];
  const float* hb  = (const float*)d_in[14];
  float* out = (float*)d_out;

  char* ws = (char*)d_ws;
  const size_t SZ_X     = (size_t)NN * D * 4;             // 12.8 MB
  const size_t OFF_WB1  = 0;
  const size_t OFF_WB2  = OFF_WB1 + 24576;
  const size_t OFF_DEG  = OFF_WB2 + 8192;
  const size_t OFF_OFFS = OFF_DEG + 200704;
  const size_t OFF_CUR  = OFF_OFFS + 200704;
  const size_t OFF_BSUM = OFF_CUR + 200704;
  const size_t OFF_SDC  = OFF_BSUM + 512;                 // 6.4 MB int2
  const size_t OFF_X1B  = OFF_SDC + (size_t)NE * 8;       // 6.4 MB
  const size_t OFF_AGG  = OFF_X1B + (size_t)NN * D * 2;   // 12.8 MB
  const size_t OFF_ECSR = OFF_AGG + SZ_X;                 // 102.4 MB
  const size_t NEED_A   = OFF_ECSR + (size_t)NE * D * 2;  // ~129 MB

  unsigned short* wB1 = (unsigned short*)(ws + OFF_WB1);
  unsigned short* wB2 = (unsigned short*)(ws + OFF_WB2);
  int* deg  = (int*)(ws + OFF_DEG);
  int* offs = (int*)(ws + OFF_OFFS);
  int* cur  = (int*)(ws + OFF_CUR);
  int* bsum = (int*)(ws + OFF_BSUM);
  int2* sdcsr = (int2*)(ws + OFF_SDC);
  unsigned short* x1b  = (unsigned short*)(ws + OFF_X1B);
  float* agg = (float*)(ws + OFF_AGG);
  unsigned short* ecsr = (unsigned short*)(ws + OFF_ECSR);

  const int* src = ei;
  const int* dst = ei + NE;

  const int nodeBlocks = (NN + 63) / 64;     // 782
  const int edgeBlocks = NE / 64;            // 12500
  const int scanBlocks = (NN + 1023) / 1024; // 49

  pack_weights_kernel<<<8, 256, 0, stream>>>(ew1, ew2, wB1, wB2);

  if (ws_size >= NEED_A) {
    // ---- CSR build (by dst) ----
    zero_int_kernel<<<(NN + 255) / 256, 256, 0, stream>>>(deg, NN);
    count_kernel<<<(NE + 255) / 256, 256, 0, stream>>>(dst, deg);
    scan_reduce_kernel<<<scanBlocks, 1024, 0, stream>>>(deg, bsum);
    scan_final_kernel<<<scanBlocks, 1024, 0, stream>>>(deg, bsum, offs, cur);

    // ---- merged fill + permute: slot assignment + sdcsr + bf16 ecsr ----
    fillperm_kernel<<<(NE * 4 + 255) / 256, 256, 0, stream>>>(
        e0, src, dst, cur, sdcsr, ecsr);

    // ---- zero layer-1 agg ----
    zero_f4_kernel<<<(NN * D / 4 + 255) / 256, 256, 0, stream>>>(
        (float4*)agg, NN * D / 4);

    // ---- layer 0: fused gather + node MLP -> x1b ----
    node_mlp_g0_kernel<<<nodeBlocks, 512, 0, stream>>>(
        x0, ecsr, sdcsr, offs, gw1, gb1, gw2, gb2, lng, lnb, x1b);

    // ---- layer-0 edge update (MFMA) + parallel segment reduce -> agg ----
    edge_mfma_seg_kernel<<<edgeBlocks, 256, 0, stream>>>(
        x1b, ecsr, sdcsr, wB1, eb1, wB2, eb2, agg);

    // ---- layer 1: plain node MLP (x1b + agg) + fused head ----
    node_mlp1_kernel<<<nodeBlocks, 512, 0, stream>>>(
        x1b, agg, gw1 + D * D, gb1 + D, gw2 + D * D, gb2 + D,
        lng + D, lnb + D, hw, hb, out);
  } else {
    // ---- fallback: atomic path (no CSR) ----
    float* x1f  = (float*)(ws + OFF_SDC);
    float* fagg = (float*)(ws + OFF_SDC + SZ_X);
    float* x2   = (float*)(ws + OFF_SDC + 2 * SZ_X);
    zero_f4_kernel<<<(NN * D / 4 + 255) / 256, 256, 0, stream>>>(
        (float4*)fagg, NN * D / 4);
    scatter_kernel<<<(NE * 16 + 255) / 256, 256, 0, stream>>>(x0, e0, src, dst, fagg);
    node_mlp_kernel<<<nodeBlocks, 256, 0, stream>>>(
        x0, fagg, gw1, gb1, gw2, gb2, lng, lnb, x1f);
    zero_f4_kernel<<<(NN * D / 4 + 255) / 256, 256, 0, stream>>>(
        (float4*)fagg, NN * D / 4);
    edge_mfma_atomic_kernel<<<edgeBlocks, 256, 0, stream>>>(
        x1f, e0, src, dst, wB1, eb1, wB2, eb2, fagg);
    node_mlp_kernel<<<nodeBlocks, 256, 0, stream>>>(
        x1f, fagg, gw1 + D * D, gb1 + D, gw2 + D * D, gb2 + D, lng + D, lnb + D, x2);
    head_kernel<<<(NN + 255) / 256, 256, 0, stream>>>(x2, hw, hb, out);
  }
}